// Round 5
// baseline (925.121 us; speedup 1.0000x reference)
//
#include <hip/hip_runtime.h>

// out = Σ_i ChebConv_i(x), K=3, normalization=None, lambda_max=2 (scale=1).
// lhat(v)[r] = (deg[r]-1)*v[r] - Σ_{e:dst=r} w_e v[src_e]
// Tx1 = lhat(x); Tx2 = 2*lhat(Tx1) - x
// out = x@ΣW[i,0] + Σ_i (Tx1_i@W[i,1] + Tx2_i@W[i,2]) + Σ_i b_i
//
// Round 5: XCD-sliced prep (kill atomic write amplification like round-4 fill),
// batched spmvB (one launch), all 7 GEMMs fused into one kernel (one C write).

#define CDIM 128

__device__ __forceinline__ float b2f(unsigned short h) {
  return __uint_as_float((unsigned)h << 16);
}
__device__ __forceinline__ unsigned short f2b(float f) {
  unsigned u = __float_as_uint(f);
  return (unsigned short)((u + 0x7FFF + ((u >> 16) & 1)) >> 16);
}

// x (f32) -> xb (bf16 pairs)
__global__ __launch_bounds__(256) void xcast_kernel(const float2* __restrict__ x,
    ushort2* __restrict__ xb, int total2) {
  int i = blockIdx.x * 256 + threadIdx.x;
  if (i >= total2) return;
  float2 v = x[i];
  xb[i] = make_ushort2(f2b(v.x), f2b(v.y));
}

// XCD-sliced deg+hist: block handles one node-slice; atomics confined to
// ~75KB/conv per slice -> L2-resident, full-line accumulation before writeback.
__global__ __launch_bounds__(256) void prep_sliced(const int* __restrict__ ei,
    const float* __restrict__ ew, float* __restrict__ deg, int* __restrict__ cnt,
    int E, int N, int NCv, float inv8) {
  const int slice = blockIdx.x & 7;
  const int g0 = (blockIdx.x >> 3) * 256 + threadIdx.x;
  const int stride = (gridDim.x >> 3) * 256;
  for (int conv = 0; conv < NCv; ++conv) {
    const int* srcv = ei + (size_t)conv * 2 * E;
    const int* dstv = srcv + E;
    const float* w = ew + (size_t)conv * E;
    float* dg = deg + (size_t)conv * N;
    int* cc = cnt + (size_t)conv * N;
    for (int e = g0; e < E; e += stride) {
      int s = srcv[e];
      int d = dstv[e];
      int ss = (int)(s * inv8); ss = ss > 7 ? 7 : ss;
      int ds = (int)(d * inv8); ds = ds > 7 ? 7 : ds;
      if (ss == slice) unsafeAtomicAdd(&dg[s], w[e]);
      if (ds == slice) atomicAdd(&cc[d], 1);
    }
  }
}

// per-conv exclusive scan (blockIdx = conv) + diag finish (diag = deg-1)
__global__ __launch_bounds__(1024) void scan_all(const int* __restrict__ cnt,
    int* __restrict__ row_ptr, int* __restrict__ pos, float* __restrict__ diag, int N) {
  int conv = blockIdx.x;
  const int* c = cnt + (size_t)conv * N;
  int* rp = row_ptr + (size_t)conv * (N + 1);
  int* ps = pos + (size_t)conv * N;
  float* dg = diag + (size_t)conv * N;
  for (int i = threadIdx.x; i < N; i += 1024) dg[i] -= 1.0f;
  __shared__ int wsum[16];
  __shared__ int carry_s;
  if (threadIdx.x == 0) carry_s = 0;
  int lane = threadIdx.x & 63, wid = threadIdx.x >> 6;
  __syncthreads();
  for (int base = 0; base < N; base += 1024) {
    int i = base + (int)threadIdx.x;
    int v = (i < N) ? c[i] : 0;
    int s = v;
    #pragma unroll
    for (int off = 1; off < 64; off <<= 1) {
      int t = __shfl_up(s, off, 64);
      if (lane >= off) s += t;
    }
    if (lane == 63) wsum[wid] = s;
    __syncthreads();
    if (wid == 0) {
      int ws = (lane < 16) ? wsum[lane] : 0;
      #pragma unroll
      for (int off = 1; off < 16; off <<= 1) {
        int t = __shfl_up(ws, off, 64);
        if (lane >= off) ws += t;
      }
      if (lane < 16) wsum[lane] = ws;
    }
    __syncthreads();
    int woff = (wid == 0) ? 0 : wsum[wid - 1];
    int excl = carry_s + woff + s - v;
    if (i < N) { rp[i] = excl; ps[i] = excl; }
    __syncthreads();
    if (threadIdx.x == 0) carry_s += wsum[15];
    __syncthreads();
  }
  if (threadIdx.x == 0) rp[N] = carry_s;
}

// w0s = Σ_i W[i,0]; bs = Σ_i b[i]
__global__ __launch_bounds__(256) void wsum_kernel(const float* __restrict__ W,
    const float* __restrict__ b, float* __restrict__ w0s, float* __restrict__ bs,
    int KK, int NCv) {
  int p = blockIdx.x * 256 + threadIdx.x;
  if (p < CDIM * CDIM) {
    float s = 0.f;
    for (int i = 0; i < NCv; ++i) s += W[(size_t)i * KK * CDIM * CDIM + p];
    w0s[p] = s;
  }
  if (p < CDIM) {
    float s = 0.f;
    for (int i = 0; i < NCv; ++i) s += b[i * CDIM + p];
    bs[p] = s;
  }
}

// XCD-sliced CSR fill (see round 4)
__global__ __launch_bounds__(256) void fill_sliced(const int* __restrict__ ei,
    const float* __restrict__ ew, int* __restrict__ pos, int2* __restrict__ srcw,
    int E, int N, int NCv, float inv8) {
  const int slice = blockIdx.x & 7;
  const int g0 = (blockIdx.x >> 3) * 256 + threadIdx.x;
  const int stride = (gridDim.x >> 3) * 256;
  for (int conv = 0; conv < NCv; ++conv) {
    const int* srcv = ei + (size_t)conv * 2 * E;
    const int* dstv = srcv + E;
    const float* w = ew + (size_t)conv * E;
    int* ps = pos + (size_t)conv * N;
    int2* sw = srcw + (size_t)conv * E;
    for (int e = g0; e < E; e += stride) {
      int d = dstv[e];
      int s = (int)(d * inv8);
      s = s > 7 ? 7 : s;
      if (s != slice) continue;
      int p = atomicAdd(&ps[d], 1);
      sw[p] = make_int2(srcv[e], __float_as_int(w[e]));
    }
  }
}

// Tx1_i = lhat_i(x) for all convs. 2 rows per wave: 32 lanes x ushort4 per row.
__global__ __launch_bounds__(256) void spmvA(const int* __restrict__ row_ptr,
    const int2* __restrict__ srcw, const float* __restrict__ diag,
    const ushort4* __restrict__ xb, ushort4* __restrict__ tx1b, int N, int E, int NCv) {
  int rg = blockIdx.x * 8 + ((int)threadIdx.x >> 5);
  if (rg >= NCv * N) return;
  int conv = rg / N;
  int row = rg - conv * N;
  const int* rp = row_ptr + (size_t)conv * (N + 1);
  const int2* sw = srcw + (size_t)conv * E;
  int c4 = threadIdx.x & 31;
  float d = diag[(size_t)conv * N + row];
  ushort4 xv = xb[(size_t)row * 32 + c4];
  float a0 = d * b2f(xv.x), a1 = d * b2f(xv.y);
  float a2 = d * b2f(xv.z), a3 = d * b2f(xv.w);
  int e = rp[row], end = rp[row + 1];
  for (; e + 1 < end; e += 2) {
    int2 s0 = sw[e], s1 = sw[e + 1];
    ushort4 v0 = xb[(size_t)s0.x * 32 + c4];
    ushort4 v1 = xb[(size_t)s1.x * 32 + c4];
    float w0 = __int_as_float(s0.y), w1 = __int_as_float(s1.y);
    a0 = fmaf(-w0, b2f(v0.x), a0); a1 = fmaf(-w0, b2f(v0.y), a1);
    a2 = fmaf(-w0, b2f(v0.z), a2); a3 = fmaf(-w0, b2f(v0.w), a3);
    a0 = fmaf(-w1, b2f(v1.x), a0); a1 = fmaf(-w1, b2f(v1.y), a1);
    a2 = fmaf(-w1, b2f(v1.z), a2); a3 = fmaf(-w1, b2f(v1.w), a3);
  }
  if (e < end) {
    int2 s0 = sw[e];
    ushort4 v0 = xb[(size_t)s0.x * 32 + c4];
    float w0 = __int_as_float(s0.y);
    a0 = fmaf(-w0, b2f(v0.x), a0); a1 = fmaf(-w0, b2f(v0.y), a1);
    a2 = fmaf(-w0, b2f(v0.z), a2); a3 = fmaf(-w0, b2f(v0.w), a3);
  }
  tx1b[((size_t)conv * N + row) * 32 + c4] =
      make_ushort4(f2b(a0), f2b(a1), f2b(a2), f2b(a3));
}

// Tx2_i = 2*lhat_i(Tx1_i) - x for conv batch (NCv convs in one launch)
__global__ __launch_bounds__(256) void spmvB_all(const int* __restrict__ row_ptr,
    const int2* __restrict__ srcw, const float* __restrict__ diag,
    const ushort4* __restrict__ t1all, const ushort4* __restrict__ xb,
    ushort4* __restrict__ t2all, int N, int E, int NCv) {
  int rg = blockIdx.x * 8 + ((int)threadIdx.x >> 5);
  if (rg >= NCv * N) return;
  int conv = rg / N;
  int row = rg - conv * N;
  const int* rp = row_ptr + (size_t)conv * (N + 1);
  const int2* sw = srcw + (size_t)conv * E;
  const ushort4* t1 = t1all + (size_t)conv * N * 32;
  int c4 = threadIdx.x & 31;
  float d = diag[(size_t)conv * N + row];
  ushort4 tv = t1[(size_t)row * 32 + c4];
  float a0 = d * b2f(tv.x), a1 = d * b2f(tv.y);
  float a2 = d * b2f(tv.z), a3 = d * b2f(tv.w);
  int e = rp[row], end = rp[row + 1];
  for (; e + 1 < end; e += 2) {
    int2 s0 = sw[e], s1 = sw[e + 1];
    ushort4 v0 = t1[(size_t)s0.x * 32 + c4];
    ushort4 v1 = t1[(size_t)s1.x * 32 + c4];
    float w0 = __int_as_float(s0.y), w1 = __int_as_float(s1.y);
    a0 = fmaf(-w0, b2f(v0.x), a0); a1 = fmaf(-w0, b2f(v0.y), a1);
    a2 = fmaf(-w0, b2f(v0.z), a2); a3 = fmaf(-w0, b2f(v0.w), a3);
    a0 = fmaf(-w1, b2f(v1.x), a0); a1 = fmaf(-w1, b2f(v1.y), a1);
    a2 = fmaf(-w1, b2f(v1.z), a2); a3 = fmaf(-w1, b2f(v1.w), a3);
  }
  if (e < end) {
    int2 s0 = sw[e];
    ushort4 v0 = t1[(size_t)s0.x * 32 + c4];
    float w0 = __int_as_float(s0.y);
    a0 = fmaf(-w0, b2f(v0.x), a0); a1 = fmaf(-w0, b2f(v0.y), a1);
    a2 = fmaf(-w0, b2f(v0.z), a2); a3 = fmaf(-w0, b2f(v0.w), a3);
  }
  ushort4 xv = xb[(size_t)row * 32 + c4];
  a0 = 2.f * a0 - b2f(xv.x); a1 = 2.f * a1 - b2f(xv.y);
  a2 = 2.f * a2 - b2f(xv.z); a3 = 2.f * a3 - b2f(xv.w);
  t2all[((size_t)conv * N + row) * 32 + c4] =
      make_ushort4(f2b(a0), f2b(a1), f2b(a2), f2b(a3));
}

// C = bias + xb@w0s + Σ_i (t1_i@W[i,1] + t2_i@W[i,2])  — one write, no RMW.
__global__ __launch_bounds__(256) void gemm_fused(const ushort2* __restrict__ xb,
    const ushort2* __restrict__ t1all, const ushort2* __restrict__ t2all,
    const float* __restrict__ w0s, const float* __restrict__ W,
    const float* __restrict__ bs, float* __restrict__ C, int N, int KK, int NCv) {
  __shared__ float Al[32 * CDIM];
  int t = threadIdx.x;
  int row0 = blockIdx.x * 32;
  int c = t & 127;
  int rb = (t >> 7) * 16;
  float acc[16];
  #pragma unroll
  for (int j = 0; j < 16; ++j) acc[j] = 0.f;
  const int stages = 1 + 2 * NCv;
  for (int s = 0; s < stages; ++s) {
    const ushort2* A;
    const float* B;
    if (s == 0) { A = xb; B = w0s; }
    else {
      int i = (s - 1) >> 1;
      int kk = 1 + ((s - 1) & 1);
      A = ((kk == 1) ? t1all : t2all) + (size_t)i * N * 64;
      B = W + (size_t)i * KK * CDIM * CDIM + (size_t)kk * CDIM * CDIM;
    }
    #pragma unroll
    for (int j = 0; j < 8; ++j) {
      int idx2 = t + j * 256;
      int rl = idx2 >> 6, c2 = idx2 & 63;
      int r = row0 + rl;
      ushort2 v = (r < N) ? A[(size_t)r * 64 + c2] : make_ushort2(0, 0);
      Al[rl * CDIM + c2 * 2] = b2f(v.x);
      Al[rl * CDIM + c2 * 2 + 1] = b2f(v.y);
    }
    __syncthreads();
    for (int k = 0; k < CDIM; k += 4) {
      float b0 = B[(k + 0) * CDIM + c];
      float b1 = B[(k + 1) * CDIM + c];
      float b2 = B[(k + 2) * CDIM + c];
      float b3 = B[(k + 3) * CDIM + c];
      #pragma unroll
      for (int j = 0; j < 16; ++j) {
        const float4 a = *reinterpret_cast<const float4*>(&Al[(rb + j) * CDIM + k]);
        acc[j] = fmaf(a.x, b0, fmaf(a.y, b1, fmaf(a.z, b2, fmaf(a.w, b3, acc[j]))));
      }
    }
    __syncthreads();
  }
  float bb = bs[c];
  #pragma unroll
  for (int j = 0; j < 16; ++j) {
    int r = row0 + rb + j;
    if (r < N) C[(size_t)r * CDIM + c] = acc[j] + bb;
  }
}

// ---- fallback path kernels (only used if ws too small for batched tx2) ----
__global__ __launch_bounds__(256) void gemm_init(const ushort2* __restrict__ A,
    const float* __restrict__ B, const float* __restrict__ bias,
    float* __restrict__ C, int N) {
  __shared__ float Al[32 * CDIM];
  int t = threadIdx.x;
  int row0 = blockIdx.x * 32;
  #pragma unroll
  for (int j = 0; j < 8; ++j) {
    int idx2 = t + j * 256;
    int rl = idx2 >> 6, c2 = idx2 & 63;
    int r = row0 + rl;
    ushort2 v = (r < N) ? A[(size_t)r * 64 + c2] : make_ushort2(0, 0);
    Al[rl * CDIM + c2 * 2] = b2f(v.x);
    Al[rl * CDIM + c2 * 2 + 1] = b2f(v.y);
  }
  __syncthreads();
  int c = t & 127;
  int rb = (t >> 7) * 16;
  float acc[16];
  #pragma unroll
  for (int j = 0; j < 16; ++j) acc[j] = 0.f;
  for (int k = 0; k < CDIM; k += 4) {
    float b0 = B[(k + 0) * CDIM + c];
    float b1 = B[(k + 1) * CDIM + c];
    float b2 = B[(k + 2) * CDIM + c];
    float b3 = B[(k + 3) * CDIM + c];
    #pragma unroll
    for (int j = 0; j < 16; ++j) {
      const float4 a = *reinterpret_cast<const float4*>(&Al[(rb + j) * CDIM + k]);
      acc[j] = fmaf(a.x, b0, fmaf(a.y, b1, fmaf(a.z, b2, fmaf(a.w, b3, acc[j]))));
    }
  }
  float bb = bias[c];
  #pragma unroll
  for (int j = 0; j < 16; ++j) {
    int r = row0 + rb + j;
    if (r < N) C[(size_t)r * CDIM + c] = acc[j] + bb;
  }
}

__global__ __launch_bounds__(256) void gemm2(const ushort2* __restrict__ A1,
    const ushort2* __restrict__ A2, const float* __restrict__ B1,
    const float* __restrict__ B2, float* __restrict__ C, int N) {
  __shared__ float Al[2 * 32 * CDIM];
  int t = threadIdx.x;
  int row0 = blockIdx.x * 32;
  #pragma unroll
  for (int j = 0; j < 8; ++j) {
    int idx2 = t + j * 256;
    int rl = idx2 >> 6, c2 = idx2 & 63;
    int r = row0 + rl;
    ushort2 v1 = (r < N) ? A1[(size_t)r * 64 + c2] : make_ushort2(0, 0);
    ushort2 v2 = (r < N) ? A2[(size_t)r * 64 + c2] : make_ushort2(0, 0);
    Al[rl * CDIM + c2 * 2]     = b2f(v1.x);
    Al[rl * CDIM + c2 * 2 + 1] = b2f(v1.y);
    Al[4096 + rl * CDIM + c2 * 2]     = b2f(v2.x);
    Al[4096 + rl * CDIM + c2 * 2 + 1] = b2f(v2.y);
  }
  __syncthreads();
  int c = t & 127;
  int rb = (t >> 7) * 16;
  float acc[16];
  #pragma unroll
  for (int j = 0; j < 16; ++j) acc[j] = 0.f;
  for (int k = 0; k < CDIM; k += 4) {
    float b10 = B1[(k + 0) * CDIM + c];
    float b11 = B1[(k + 1) * CDIM + c];
    float b12 = B1[(k + 2) * CDIM + c];
    float b13 = B1[(k + 3) * CDIM + c];
    float b20 = B2[(k + 0) * CDIM + c];
    float b21 = B2[(k + 1) * CDIM + c];
    float b22 = B2[(k + 2) * CDIM + c];
    float b23 = B2[(k + 3) * CDIM + c];
    #pragma unroll
    for (int j = 0; j < 16; ++j) {
      const float4 a1 = *reinterpret_cast<const float4*>(&Al[(rb + j) * CDIM + k]);
      const float4 a2 = *reinterpret_cast<const float4*>(&Al[4096 + (rb + j) * CDIM + k]);
      float s = acc[j];
      s = fmaf(a1.x, b10, s); s = fmaf(a1.y, b11, s);
      s = fmaf(a1.z, b12, s); s = fmaf(a1.w, b13, s);
      s = fmaf(a2.x, b20, s); s = fmaf(a2.y, b21, s);
      s = fmaf(a2.z, b22, s); s = fmaf(a2.w, b23, s);
      acc[j] = s;
    }
  }
  #pragma unroll
  for (int j = 0; j < 16; ++j) {
    int r = row0 + rb + j;
    if (r < N) C[(size_t)r * CDIM + c] += acc[j];
  }
}

extern "C" void kernel_launch(void* const* d_in, const int* in_sizes, int n_in,
                              void* d_out, int out_size, void* d_ws, size_t ws_size,
                              hipStream_t stream) {
  const float* x  = (const float*)d_in[0];
  const int*   ei = (const int*)d_in[1];    // [NC, 2, E] int32
  const float* ew = (const float*)d_in[2];  // [NC, E]
  const float* W  = (const float*)d_in[3];  // [NC, K, 128, 128]
  const float* b  = (const float*)d_in[4];  // [NC, 128]

  const int Nn  = in_sizes[0] / CDIM;
  const int NCv = in_sizes[4] / CDIM;
  const int E   = in_sizes[2] / NCv;
  const int KK  = in_sizes[3] / (NCv * CDIM * CDIM);

  char* p = (char*)d_ws;
  auto take = [&](size_t bytes) { char* q = p; p += (bytes + 255) & ~(size_t)255; return q; };
  float* diag    = (float*)take((size_t)NCv * Nn * 4);
  int*   cntpos  = (int*)take((size_t)NCv * Nn * 4);
  int*   row_ptr = (int*)take((size_t)NCv * (Nn + 1) * 4);
  float* w0s     = (float*)take(CDIM * CDIM * 4);
  float* bs      = (float*)take(CDIM * 4);
  ushort2* xb    = (ushort2*)take((size_t)Nn * 64 * 4);
  ushort2* tx1b  = (ushort2*)take((size_t)NCv * Nn * 64 * 4);
  int2*  srcw    = (int2*)take((size_t)NCv * E * 8);
  // batched tx2 if it fits in the remaining workspace
  size_t used = (size_t)(p - (char*)d_ws);
  bool batched = used + (size_t)NCv * Nn * 64 * 4 <= ws_size;
  ushort2* tx2b = (ushort2*)take(((size_t)(batched ? NCv : 1)) * Nn * 64 * 4);

  hipMemsetAsync(diag, 0, (size_t)NCv * Nn * 4, stream);
  hipMemsetAsync(cntpos, 0, (size_t)NCv * Nn * 4, stream);

  const float inv8 = 8.0f / (float)Nn;
  xcast_kernel<<<(Nn * 64 + 255) / 256, 256, 0, stream>>>(
      (const float2*)x, xb, Nn * 64);
  prep_sliced<<<2048, 256, 0, stream>>>(ei, ew, diag, cntpos, E, Nn, NCv, inv8);
  scan_all<<<NCv, 1024, 0, stream>>>(cntpos, row_ptr, cntpos, diag, Nn);
  wsum_kernel<<<(CDIM * CDIM + 255) / 256, 256, 0, stream>>>(W, b, w0s, bs, KK, NCv);
  fill_sliced<<<2048, 256, 0, stream>>>(ei, ew, cntpos, srcw, E, Nn, NCv, inv8);

  // Tx1 for all convs in one launch (2 rows per wave)
  spmvA<<<(NCv * Nn + 7) / 8, 256, 0, stream>>>(row_ptr, srcw, diag,
      (const ushort4*)xb, (ushort4*)tx1b, Nn, E, NCv);

  const int gemm_grid = (Nn + 31) / 32;

  if (batched) {
    // Tx2 for all convs in one launch, then one fully-fused GEMM.
    spmvB_all<<<(NCv * Nn + 7) / 8, 256, 0, stream>>>(row_ptr, srcw, diag,
        (const ushort4*)tx1b, (const ushort4*)xb, (ushort4*)tx2b, Nn, E, NCv);
    gemm_fused<<<gemm_grid, 256, 0, stream>>>(xb, tx1b, tx2b, w0s, W, bs,
                                              (float*)d_out, Nn, KK, NCv);
  } else {
    gemm_init<<<gemm_grid, 256, 0, stream>>>(xb, w0s, bs, (float*)d_out, Nn);
    for (int i = 0; i < NCv; ++i) {
      const int* rp = row_ptr + (size_t)i * (Nn + 1);
      const int2* sw = srcw + (size_t)i * E;
      const float* di = diag + (size_t)i * Nn;
      const ushort2* t1 = tx1b + (size_t)i * Nn * 64;
      const float* Wi = W + (size_t)i * KK * CDIM * CDIM;
      spmvB_all<<<(Nn + 7) / 8, 256, 0, stream>>>(rp, sw, di,
          (const ushort4*)t1, (const ushort4*)xb, (ushort4*)tx2b, Nn, E, 1);
      gemm2<<<gemm_grid, 256, 0, stream>>>(t1, tx2b, Wi + (size_t)1 * CDIM * CDIM,
                                           Wi + (size_t)2 * CDIM * CDIM,
                                           (float*)d_out, Nn);
    }
  }
}

// Round 6
// 733.331 us; speedup vs baseline: 1.2615x; 1.2615x over previous
//
#include <hip/hip_runtime.h>

// out = Σ_i ChebConv_i(x), K=3, normalization=None, lambda_max=2 (scale=1).
// lhat(v)[r] = (deg[r]-1)*v[r] - Σ_{e:dst=r} w_e v[src_e]
// Tx1 = lhat(x); Tx2 = 2*lhat(Tx1) - x
// out = x@ΣW[i,0] + Σ_i (Tx1_i@W[i,1] + Tx2_i@W[i,2]) + Σ_i b_i
//
// Round 6: MFMA GEMM. Round-5 profile: gemm_fused 359us, MfmaUtil=0,
// VALUBusy=57% -> LDS-BW-bound f32 vector GEMM (4B LDS per FMA = 4x supply).
// Cast W to bf16 (transposed [n][k]) and do one 7-stage mfma_16x16x32_bf16
// GEMM with register accumulation; one C write with bias.

#define CDIM 128

typedef __attribute__((ext_vector_type(8))) short bf16x8;
typedef __attribute__((ext_vector_type(4))) float f32x4;

__device__ __forceinline__ float b2f(unsigned short h) {
  return __uint_as_float((unsigned)h << 16);
}
__device__ __forceinline__ unsigned short f2b(float f) {
  unsigned u = __float_as_uint(f);
  return (unsigned short)((u + 0x7FFF + ((u >> 16) & 1)) >> 16);
}

// x (f32) -> xb (bf16 pairs)
__global__ __launch_bounds__(256) void xcast_kernel(const float2* __restrict__ x,
    ushort2* __restrict__ xb, int total2) {
  int i = blockIdx.x * 256 + threadIdx.x;
  if (i >= total2) return;
  float2 v = x[i];
  xb[i] = make_ushort2(f2b(v.x), f2b(v.y));
}

// XCD-sliced deg+hist (atomics confined to per-slice L2-resident range)
__global__ __launch_bounds__(256) void prep_sliced(const int* __restrict__ ei,
    const float* __restrict__ ew, float* __restrict__ deg, int* __restrict__ cnt,
    int E, int N, int NCv, float inv8) {
  const int slice = blockIdx.x & 7;
  const int g0 = (blockIdx.x >> 3) * 256 + threadIdx.x;
  const int stride = (gridDim.x >> 3) * 256;
  for (int conv = 0; conv < NCv; ++conv) {
    const int* srcv = ei + (size_t)conv * 2 * E;
    const int* dstv = srcv + E;
    const float* w = ew + (size_t)conv * E;
    float* dg = deg + (size_t)conv * N;
    int* cc = cnt + (size_t)conv * N;
    for (int e = g0; e < E; e += stride) {
      int s = srcv[e];
      int d = dstv[e];
      int ss = (int)(s * inv8); ss = ss > 7 ? 7 : ss;
      int ds = (int)(d * inv8); ds = ds > 7 ? 7 : ds;
      if (ss == slice) unsafeAtomicAdd(&dg[s], w[e]);
      if (ds == slice) atomicAdd(&cc[d], 1);
    }
  }
}

// per-conv exclusive scan (blockIdx = conv) + diag finish (diag = deg-1)
__global__ __launch_bounds__(1024) void scan_all(const int* __restrict__ cnt,
    int* __restrict__ row_ptr, int* __restrict__ pos, float* __restrict__ diag, int N) {
  int conv = blockIdx.x;
  const int* c = cnt + (size_t)conv * N;
  int* rp = row_ptr + (size_t)conv * (N + 1);
  int* ps = pos + (size_t)conv * N;
  float* dg = diag + (size_t)conv * N;
  for (int i = threadIdx.x; i < N; i += 1024) dg[i] -= 1.0f;
  __shared__ int wsum[16];
  __shared__ int carry_s;
  if (threadIdx.x == 0) carry_s = 0;
  int lane = threadIdx.x & 63, wid = threadIdx.x >> 6;
  __syncthreads();
  for (int base = 0; base < N; base += 1024) {
    int i = base + (int)threadIdx.x;
    int v = (i < N) ? c[i] : 0;
    int s = v;
    #pragma unroll
    for (int off = 1; off < 64; off <<= 1) {
      int t = __shfl_up(s, off, 64);
      if (lane >= off) s += t;
    }
    if (lane == 63) wsum[wid] = s;
    __syncthreads();
    if (wid == 0) {
      int ws = (lane < 16) ? wsum[lane] : 0;
      #pragma unroll
      for (int off = 1; off < 16; off <<= 1) {
        int t = __shfl_up(ws, off, 64);
        if (lane >= off) ws += t;
      }
      if (lane < 16) wsum[lane] = ws;
    }
    __syncthreads();
    int woff = (wid == 0) ? 0 : wsum[wid - 1];
    int excl = carry_s + woff + s - v;
    if (i < N) { rp[i] = excl; ps[i] = excl; }
    __syncthreads();
    if (threadIdx.x == 0) carry_s += wsum[15];
    __syncthreads();
  }
  if (threadIdx.x == 0) rp[N] = carry_s;
}

// Wtb[s][n][k] (bf16, transposed weights) for the 7 GEMM stages; bs = Σ b_i.
// stage 0: Σ_i W[i,0]; stage 2i+1: W[i,1]; stage 2i+2: W[i,2]
__global__ __launch_bounds__(256) void wcast_kernel(const float* __restrict__ W,
    const float* __restrict__ b, unsigned short* __restrict__ Wtb,
    float* __restrict__ bs, int KK, int NCv) {
  int p = blockIdx.x * 256 + threadIdx.x;
  const int stages = 1 + 2 * NCv;
  if (p < stages * CDIM * CDIM) {
    int s = p >> 14;
    int nk = p & 16383;
    int n = nk >> 7, k = nk & 127;
    float v;
    if (s == 0) {
      v = 0.f;
      for (int i = 0; i < NCv; ++i)
        v += W[(size_t)i * KK * CDIM * CDIM + (size_t)k * CDIM + n];
    } else {
      int i, kk;
      if (s & 1) { i = (s - 1) >> 1; kk = 1; }
      else       { i = (s >> 1) - 1; kk = 2; }
      v = W[(size_t)i * KK * CDIM * CDIM + (size_t)kk * CDIM * CDIM + (size_t)k * CDIM + n];
    }
    Wtb[p] = f2b(v);
  }
  if (p < CDIM) {
    float s = 0.f;
    for (int i = 0; i < NCv; ++i) s += b[i * CDIM + p];
    bs[p] = s;
  }
}

// XCD-sliced CSR fill
__global__ __launch_bounds__(256) void fill_sliced(const int* __restrict__ ei,
    const float* __restrict__ ew, int* __restrict__ pos, int2* __restrict__ srcw,
    int E, int N, int NCv, float inv8) {
  const int slice = blockIdx.x & 7;
  const int g0 = (blockIdx.x >> 3) * 256 + threadIdx.x;
  const int stride = (gridDim.x >> 3) * 256;
  for (int conv = 0; conv < NCv; ++conv) {
    const int* srcv = ei + (size_t)conv * 2 * E;
    const int* dstv = srcv + E;
    const float* w = ew + (size_t)conv * E;
    int* ps = pos + (size_t)conv * N;
    int2* sw = srcw + (size_t)conv * E;
    for (int e = g0; e < E; e += stride) {
      int d = dstv[e];
      int s = (int)(d * inv8);
      s = s > 7 ? 7 : s;
      if (s != slice) continue;
      int p = atomicAdd(&ps[d], 1);
      sw[p] = make_int2(srcv[e], __float_as_int(w[e]));
    }
  }
}

// Tx1_i = lhat_i(x) for all convs. 2 rows per wave: 32 lanes x ushort4 per row.
__global__ __launch_bounds__(256) void spmvA(const int* __restrict__ row_ptr,
    const int2* __restrict__ srcw, const float* __restrict__ diag,
    const ushort4* __restrict__ xb, ushort4* __restrict__ tx1b, int N, int E, int NCv) {
  int rg = blockIdx.x * 8 + ((int)threadIdx.x >> 5);
  if (rg >= NCv * N) return;
  int conv = rg / N;
  int row = rg - conv * N;
  const int* rp = row_ptr + (size_t)conv * (N + 1);
  const int2* sw = srcw + (size_t)conv * E;
  int c4 = threadIdx.x & 31;
  float d = diag[(size_t)conv * N + row];
  ushort4 xv = xb[(size_t)row * 32 + c4];
  float a0 = d * b2f(xv.x), a1 = d * b2f(xv.y);
  float a2 = d * b2f(xv.z), a3 = d * b2f(xv.w);
  int e = rp[row], end = rp[row + 1];
  for (; e + 1 < end; e += 2) {
    int2 s0 = sw[e], s1 = sw[e + 1];
    ushort4 v0 = xb[(size_t)s0.x * 32 + c4];
    ushort4 v1 = xb[(size_t)s1.x * 32 + c4];
    float w0 = __int_as_float(s0.y), w1 = __int_as_float(s1.y);
    a0 = fmaf(-w0, b2f(v0.x), a0); a1 = fmaf(-w0, b2f(v0.y), a1);
    a2 = fmaf(-w0, b2f(v0.z), a2); a3 = fmaf(-w0, b2f(v0.w), a3);
    a0 = fmaf(-w1, b2f(v1.x), a0); a1 = fmaf(-w1, b2f(v1.y), a1);
    a2 = fmaf(-w1, b2f(v1.z), a2); a3 = fmaf(-w1, b2f(v1.w), a3);
  }
  if (e < end) {
    int2 s0 = sw[e];
    ushort4 v0 = xb[(size_t)s0.x * 32 + c4];
    float w0 = __int_as_float(s0.y);
    a0 = fmaf(-w0, b2f(v0.x), a0); a1 = fmaf(-w0, b2f(v0.y), a1);
    a2 = fmaf(-w0, b2f(v0.z), a2); a3 = fmaf(-w0, b2f(v0.w), a3);
  }
  tx1b[((size_t)conv * N + row) * 32 + c4] =
      make_ushort4(f2b(a0), f2b(a1), f2b(a2), f2b(a3));
}

// Tx2_i = 2*lhat_i(Tx1_i) - x for all convs in one launch
__global__ __launch_bounds__(256) void spmvB_all(const int* __restrict__ row_ptr,
    const int2* __restrict__ srcw, const float* __restrict__ diag,
    const ushort4* __restrict__ t1all, const ushort4* __restrict__ xb,
    ushort4* __restrict__ t2all, int N, int E, int NCv) {
  int rg = blockIdx.x * 8 + ((int)threadIdx.x >> 5);
  if (rg >= NCv * N) return;
  int conv = rg / N;
  int row = rg - conv * N;
  const int* rp = row_ptr + (size_t)conv * (N + 1);
  const int2* sw = srcw + (size_t)conv * E;
  const ushort4* t1 = t1all + (size_t)conv * N * 32;
  int c4 = threadIdx.x & 31;
  float d = diag[(size_t)conv * N + row];
  ushort4 tv = t1[(size_t)row * 32 + c4];
  float a0 = d * b2f(tv.x), a1 = d * b2f(tv.y);
  float a2 = d * b2f(tv.z), a3 = d * b2f(tv.w);
  int e = rp[row], end = rp[row + 1];
  for (; e + 1 < end; e += 2) {
    int2 s0 = sw[e], s1 = sw[e + 1];
    ushort4 v0 = t1[(size_t)s0.x * 32 + c4];
    ushort4 v1 = t1[(size_t)s1.x * 32 + c4];
    float w0 = __int_as_float(s0.y), w1 = __int_as_float(s1.y);
    a0 = fmaf(-w0, b2f(v0.x), a0); a1 = fmaf(-w0, b2f(v0.y), a1);
    a2 = fmaf(-w0, b2f(v0.z), a2); a3 = fmaf(-w0, b2f(v0.w), a3);
    a0 = fmaf(-w1, b2f(v1.x), a0); a1 = fmaf(-w1, b2f(v1.y), a1);
    a2 = fmaf(-w1, b2f(v1.z), a2); a3 = fmaf(-w1, b2f(v1.w), a3);
  }
  if (e < end) {
    int2 s0 = sw[e];
    ushort4 v0 = t1[(size_t)s0.x * 32 + c4];
    float w0 = __int_as_float(s0.y);
    a0 = fmaf(-w0, b2f(v0.x), a0); a1 = fmaf(-w0, b2f(v0.y), a1);
    a2 = fmaf(-w0, b2f(v0.z), a2); a3 = fmaf(-w0, b2f(v0.w), a3);
  }
  ushort4 xv = xb[(size_t)row * 32 + c4];
  a0 = 2.f * a0 - b2f(xv.x); a1 = 2.f * a1 - b2f(xv.y);
  a2 = 2.f * a2 - b2f(xv.z); a3 = 2.f * a3 - b2f(xv.w);
  t2all[((size_t)conv * N + row) * 32 + c4] =
      make_ushort4(f2b(a0), f2b(a1), f2b(a2), f2b(a3));
}

// MFMA GEMM: C = bias + Σ_s A_s @ W_s  over 1+2*NCv stages.
// Block = 64 rows, 4 waves; wave w owns rows r0+w*16 .. +15, all 128 cols.
// A-frag (16x32): lane holds A[l&15][(l>>4)*8 + j], contiguous 16B load.
// B-frag (32x16): lane holds B[(l>>4)*8+j][l&15] = Wtb[col][k] (Wtb is [n][k]).
// D (16x16): col = l&15, row = (l>>4)*4 + reg   [guide §3, m89-verified]
__global__ __launch_bounds__(256) void gemm_mfma(const unsigned short* __restrict__ xb,
    const unsigned short* __restrict__ t1all, const unsigned short* __restrict__ t2all,
    const unsigned short* __restrict__ Wtb, const float* __restrict__ bs,
    float* __restrict__ C, int N, int NCv) {
  const int wid = threadIdx.x >> 6;
  const int lane = threadIdx.x & 63;
  const int lr = lane & 15;   // A-row within tile / B&D-col within tile
  const int lk = lane >> 4;   // k-group
  const int r0 = blockIdx.x * 64 + wid * 16;
  f32x4 acc[8];
  #pragma unroll
  for (int nt = 0; nt < 8; ++nt) acc[nt] = (f32x4){0.f, 0.f, 0.f, 0.f};

  const int stages = 1 + 2 * NCv;
  int ra = r0 + lr;
  ra = ra < N ? ra : N - 1;  // clamp: garbage rows only feed unstored D rows
  for (int s = 0; s < stages; ++s) {
    const unsigned short* A;
    if (s == 0) A = xb;
    else if (s & 1) A = t1all + (size_t)((s - 1) >> 1) * N * CDIM;
    else A = t2all + (size_t)((s >> 1) - 1) * N * CDIM;
    const unsigned short* Ap = A + (size_t)ra * CDIM + lk * 8;
    bf16x8 af0 = *(const bf16x8*)(Ap);
    bf16x8 af1 = *(const bf16x8*)(Ap + 32);
    bf16x8 af2 = *(const bf16x8*)(Ap + 64);
    bf16x8 af3 = *(const bf16x8*)(Ap + 96);
    const unsigned short* Wp = Wtb + (size_t)s * CDIM * CDIM + (size_t)lr * CDIM + lk * 8;
    #pragma unroll
    for (int nt = 0; nt < 8; ++nt) {
      const unsigned short* Wn = Wp + nt * 16 * CDIM;
      acc[nt] = __builtin_amdgcn_mfma_f32_16x16x32_bf16(
          af0, *(const bf16x8*)(Wn), acc[nt], 0, 0, 0);
      acc[nt] = __builtin_amdgcn_mfma_f32_16x16x32_bf16(
          af1, *(const bf16x8*)(Wn + 32), acc[nt], 0, 0, 0);
      acc[nt] = __builtin_amdgcn_mfma_f32_16x16x32_bf16(
          af2, *(const bf16x8*)(Wn + 64), acc[nt], 0, 0, 0);
      acc[nt] = __builtin_amdgcn_mfma_f32_16x16x32_bf16(
          af3, *(const bf16x8*)(Wn + 96), acc[nt], 0, 0, 0);
    }
  }
  const int orow = r0 + lk * 4;
  #pragma unroll
  for (int nt = 0; nt < 8; ++nt) {
    int col = nt * 16 + lr;
    float bb = bs[col];
    #pragma unroll
    for (int reg = 0; reg < 4; ++reg) {
      int r = orow + reg;
      if (r < N) C[(size_t)r * CDIM + col] = acc[nt][reg] + bb;
    }
  }
}

extern "C" void kernel_launch(void* const* d_in, const int* in_sizes, int n_in,
                              void* d_out, int out_size, void* d_ws, size_t ws_size,
                              hipStream_t stream) {
  const float* x  = (const float*)d_in[0];
  const int*   ei = (const int*)d_in[1];    // [NC, 2, E] int32
  const float* ew = (const float*)d_in[2];  // [NC, E]
  const float* W  = (const float*)d_in[3];  // [NC, K, 128, 128]
  const float* b  = (const float*)d_in[4];  // [NC, 128]

  const int Nn  = in_sizes[0] / CDIM;
  const int NCv = in_sizes[4] / CDIM;
  const int E   = in_sizes[2] / NCv;
  const int KK  = in_sizes[3] / (NCv * CDIM * CDIM);
  const int stages = 1 + 2 * NCv;

  char* p = (char*)d_ws;
  auto take = [&](size_t bytes) { char* q = p; p += (bytes + 255) & ~(size_t)255; return q; };
  float* diag    = (float*)take((size_t)NCv * Nn * 4);
  int*   cntpos  = (int*)take((size_t)NCv * Nn * 4);
  int*   row_ptr = (int*)take((size_t)NCv * (Nn + 1) * 4);
  unsigned short* Wtb = (unsigned short*)take((size_t)stages * CDIM * CDIM * 2);
  float* bs      = (float*)take(CDIM * 4);
  ushort2* xb    = (ushort2*)take((size_t)Nn * 64 * 4);
  ushort2* tx1b  = (ushort2*)take((size_t)NCv * Nn * 64 * 4);
  ushort2* tx2b  = (ushort2*)take((size_t)NCv * Nn * 64 * 4);
  int2*  srcw    = (int2*)take((size_t)NCv * E * 8);

  hipMemsetAsync(diag, 0, (size_t)NCv * Nn * 4, stream);
  hipMemsetAsync(cntpos, 0, (size_t)NCv * Nn * 4, stream);

  const float inv8 = 8.0f / (float)Nn;
  xcast_kernel<<<(Nn * 64 + 255) / 256, 256, 0, stream>>>(
      (const float2*)x, xb, Nn * 64);
  prep_sliced<<<2048, 256, 0, stream>>>(ei, ew, diag, cntpos, E, Nn, NCv, inv8);
  scan_all<<<NCv, 1024, 0, stream>>>(cntpos, row_ptr, cntpos, diag, Nn);
  wcast_kernel<<<(stages * CDIM * CDIM + 255) / 256, 256, 0, stream>>>(
      W, b, Wtb, bs, KK, NCv);
  fill_sliced<<<2048, 256, 0, stream>>>(ei, ew, cntpos, srcw, E, Nn, NCv, inv8);

  spmvA<<<(NCv * Nn + 7) / 8, 256, 0, stream>>>(row_ptr, srcw, diag,
      (const ushort4*)xb, (ushort4*)tx1b, Nn, E, NCv);
  spmvB_all<<<(NCv * Nn + 7) / 8, 256, 0, stream>>>(row_ptr, srcw, diag,
      (const ushort4*)tx1b, (const ushort4*)xb, (ushort4*)tx2b, Nn, E, NCv);

  gemm_mfma<<<(Nn + 63) / 64, 256, 0, stream>>>(
      (const unsigned short*)xb, (const unsigned short*)tx1b,
      (const unsigned short*)tx2b, Wtb, bs, (float*)d_out, Nn, NCv);
}

// Round 7
// 546.579 us; speedup vs baseline: 1.6926x; 1.3417x over previous
//
#include <hip/hip_runtime.h>

// out = Σ_i ChebConv_i(x), K=3, normalization=None, lambda_max=2 (scale=1).
// lhat(v)[r] = (deg[r]-1)*v[r] - Σ_{e:dst=r} w_e v[src_e]
// Tx1 = lhat(x); Tx2 = 2*lhat(Tx1) - x
// out = x@ΣW[i,0] + Σ_i (Tx1_i@W[i,1] + Tx2_i@W[i,2]) + Σ_i b_i
//
// Round 7: kill per-edge global atomics (r6 profile: prep 238us, WRITE=149MB
// = 32B fabric transaction PER ATOMIC; device-scope atomics bypass L2, so
// XCD-slicing can't help). Radix scheme: coarse LDS hist -> bucket partition
// (contiguous per-block runs) -> per-bucket finalize (LDS hist+scan, writes
// row_ptr/diag/CSR with zero global atomics). CSR records 4B (u16 src, bf16 w).
// Requires N < 65536 (here N=50000).

#define CDIM 128
#define RANGE 4096
#define RSH 12
#define MAXNR 32

typedef __attribute__((ext_vector_type(8))) short bf16x8;
typedef __attribute__((ext_vector_type(4))) float f32x4;

__device__ __forceinline__ float b2f(unsigned short h) {
  return __uint_as_float((unsigned)h << 16);
}
__device__ __forceinline__ unsigned short f2b(float f) {
  unsigned u = __float_as_uint(f);
  return (unsigned short)((u + 0x7FFF + ((u >> 16) & 1)) >> 16);
}

// x (f32) -> xb (bf16 pairs)
__global__ __launch_bounds__(256) void xcast_kernel(const float2* __restrict__ x,
    ushort2* __restrict__ xb, int total2) {
  int i = blockIdx.x * 256 + threadIdx.x;
  if (i >= total2) return;
  float2 v = x[i];
  xb[i] = make_ushort2(f2b(v.x), f2b(v.y));
}

// Wtb[s][n][k] (bf16, transposed weights) for the 1+2*NCv GEMM stages; bs = Σ b_i.
__global__ __launch_bounds__(256) void wcast_kernel(const float* __restrict__ W,
    const float* __restrict__ b, unsigned short* __restrict__ Wtb,
    float* __restrict__ bs, int KK, int NCv) {
  int p = blockIdx.x * 256 + threadIdx.x;
  const int stages = 1 + 2 * NCv;
  if (p < stages * CDIM * CDIM) {
    int s = p >> 14;
    int nk = p & 16383;
    int n = nk >> 7, k = nk & 127;
    float v;
    if (s == 0) {
      v = 0.f;
      for (int i = 0; i < NCv; ++i)
        v += W[(size_t)i * KK * CDIM * CDIM + (size_t)k * CDIM + n];
    } else {
      int i, kk;
      if (s & 1) { i = (s - 1) >> 1; kk = 1; }
      else       { i = (s >> 1) - 1; kk = 2; }
      v = W[(size_t)i * KK * CDIM * CDIM + (size_t)kk * CDIM * CDIM + (size_t)k * CDIM + n];
    }
    Wtb[p] = f2b(v);
  }
  if (p < CDIM) {
    float s = 0.f;
    for (int i = 0; i < NCv; ++i) s += b[i * CDIM + p];
    bs[p] = s;
  }
}

// coarse per-bucket counts of src and dst, LDS-aggregated
// coarse layout: [conv][2][MAXNR]  (axis 0 = src, 1 = dst)
__global__ __launch_bounds__(256) void hist_coarse(const int* __restrict__ ei,
    int* __restrict__ coarse, int E, int NCv, int nr) {
  __shared__ int h[2 * MAXNR];
  int t = threadIdx.x;
  int g0 = blockIdx.x * 256 + t;
  int stride = gridDim.x * 256;
  for (int conv = 0; conv < NCv; ++conv) {
    if (t < 2 * MAXNR) h[t] = 0;
    __syncthreads();
    const int* srcv = ei + (size_t)conv * 2 * E;
    const int* dstv = srcv + E;
    for (int e = g0; e < E; e += stride) {
      atomicAdd(&h[srcv[e] >> RSH], 1);
      atomicAdd(&h[MAXNR + (dstv[e] >> RSH)], 1);
    }
    __syncthreads();
    if (t < nr) {
      if (h[t]) atomicAdd(&coarse[(conv * 2 + 0) * MAXNR + t], h[t]);
      if (h[MAXNR + t]) atomicAdd(&coarse[(conv * 2 + 1) * MAXNR + t], h[MAXNR + t]);
    }
    __syncthreads();
  }
}

// tiny serial scans: bases_d/s[conv][0..nr], cursors init = bases
__global__ __launch_bounds__(64) void scan_coarse(const int* __restrict__ coarse,
    int* __restrict__ bases_s, int* __restrict__ bases_d,
    int* __restrict__ cur_s, int* __restrict__ cur_d, int NCv, int nr) {
  int t = threadIdx.x;
  if (t >= NCv * 2) return;
  int conv = t >> 1, ax = t & 1;
  const int* c = coarse + (conv * 2 + ax) * MAXNR;
  int* bases = (ax ? bases_d : bases_s) + conv * (MAXNR + 1);
  int* cur = (ax ? cur_d : cur_s) + conv * MAXNR;
  int acc = 0;
  for (int b = 0; b < nr; ++b) {
    bases[b] = acc; cur[b] = acc; acc += c[b];
  }
  bases[nr] = acc;
}

// partition edges into node-range buckets. Per block: LDS count -> one global
// atomic per bucket to grab a contiguous run -> LDS-cursor placement.
// D record (dst-bucketed): (src u16, dst u16, w bf16, 0). S record: (src u16, w bf16).
__global__ __launch_bounds__(256) void partition_kernel(const int* __restrict__ ei,
    const float* __restrict__ ew, int* __restrict__ cur_d, int* __restrict__ cur_s,
    ushort4* __restrict__ D, ushort2* __restrict__ S, int E, int CE, int P,
    int NCv, int nr) {
  __shared__ int ld[MAXNR], ls[MAXNR], cd[MAXNR], cs[MAXNR];
  int conv = blockIdx.x / P;
  int pck = blockIdx.x - conv * P;
  int e0 = pck * CE;
  int e1 = min(E, e0 + CE);
  int t = threadIdx.x;
  const int* srcv = ei + (size_t)conv * 2 * E;
  const int* dstv = srcv + E;
  const float* w = ew + (size_t)conv * E;
  if (t < MAXNR) { ld[t] = 0; ls[t] = 0; }
  __syncthreads();
  for (int e = e0 + t; e < e1; e += 256) {
    atomicAdd(&ld[dstv[e] >> RSH], 1);
    atomicAdd(&ls[srcv[e] >> RSH], 1);
  }
  __syncthreads();
  if (t < nr) {
    cd[t] = ld[t] ? atomicAdd(&cur_d[conv * MAXNR + t], ld[t]) : 0;
    cs[t] = ls[t] ? atomicAdd(&cur_s[conv * MAXNR + t], ls[t]) : 0;
  }
  __syncthreads();
  ushort4* Dc = D + (size_t)conv * E;
  ushort2* Sc = S + (size_t)conv * E;
  for (int e = e0 + t; e < e1; e += 256) {
    int s = srcv[e], d = dstv[e];
    unsigned short wb = f2b(w[e]);
    int pd = atomicAdd(&cd[d >> RSH], 1);
    Dc[pd] = make_ushort4((unsigned short)s, (unsigned short)d, wb, 0);
    int ps = atomicAdd(&cs[s >> RSH], 1);
    Sc[ps] = make_ushort2((unsigned short)s, wb);
  }
}

// per (conv, bucket): LDS fine hist of dst + float deg of src; block scan;
// write row_ptr & diag; place CSR records via LDS cursors. No global atomics.
__global__ __launch_bounds__(1024) void finalize_kernel(const ushort4* __restrict__ D,
    const ushort2* __restrict__ S, const int* __restrict__ bases_d,
    const int* __restrict__ bases_s, int* __restrict__ row_ptr,
    float* __restrict__ diag, ushort2* __restrict__ srcw, int E, int N,
    int NCv, int nr) {
  __shared__ unsigned int hist[RANGE];
  __shared__ float fdeg[RANGE];
  __shared__ unsigned int wls[16];
  int conv = blockIdx.x / nr;
  int b = blockIdx.x - conv * nr;
  int t = threadIdx.x;
  for (int j = t; j < RANGE; j += 1024) { hist[j] = 0u; fdeg[j] = 0.f; }
  __syncthreads();
  int db0 = bases_d[conv * (MAXNR + 1) + b], db1 = bases_d[conv * (MAXNR + 1) + b + 1];
  int sb0 = bases_s[conv * (MAXNR + 1) + b], sb1 = bases_s[conv * (MAXNR + 1) + b + 1];
  const ushort4* Dc = D + (size_t)conv * E;
  const ushort2* Sc = S + (size_t)conv * E;
  for (int i = db0 + t; i < db1; i += 1024)
    atomicAdd(&hist[Dc[i].y & (RANGE - 1)], 1u);
  for (int i = sb0 + t; i < sb1; i += 1024) {
    ushort2 r = Sc[i];
    atomicAdd(&fdeg[r.x & (RANGE - 1)], b2f(r.y));
  }
  __syncthreads();
  // block exclusive scan of hist[0..RANGE): 1024 threads x 4 elems
  unsigned int v0 = hist[4 * t], v1 = hist[4 * t + 1], v2 = hist[4 * t + 2],
               v3 = hist[4 * t + 3];
  unsigned int s = v0 + v1 + v2 + v3;
  int lane = t & 63, wid = t >> 6;
  unsigned int incl = s;
  #pragma unroll
  for (int off = 1; off < 64; off <<= 1) {
    unsigned int tmp = __shfl_up((int)incl, off, 64);
    if (lane >= off) incl += tmp;
  }
  if (lane == 63) wls[wid] = incl;
  __syncthreads();
  if (wid == 0) {
    unsigned int x = (lane < 16) ? wls[lane] : 0u;
    #pragma unroll
    for (int off = 1; off < 16; off <<= 1) {
      unsigned int tmp = __shfl_up((int)x, off, 64);
      if (lane >= off) x += tmp;
    }
    if (lane < 16) wls[lane] = x;
  }
  __syncthreads();
  unsigned int base = (wid ? wls[wid - 1] : 0u) + (incl - s);
  hist[4 * t] = base;
  hist[4 * t + 1] = base + v0;
  hist[4 * t + 2] = base + v0 + v1;
  hist[4 * t + 3] = base + v0 + v1 + v2;
  __syncthreads();
  // row_ptr (positions within conv's CSR segment) + diag
  int n0 = b << RSH;
  int* rp = row_ptr + (size_t)conv * (N + 1);
  float* dg = diag + (size_t)conv * N;
  for (int j = t; j < RANGE; j += 1024) {
    int n = n0 + j;
    if (n < N) {
      rp[n] = db0 + (int)hist[j];
      dg[n] = fdeg[j] - 1.0f;
    }
  }
  if (b == nr - 1 && t == 0) rp[N] = E;
  __syncthreads();
  // place records (hist now serves as cursors)
  ushort2* swc = srcw + (size_t)conv * E;
  for (int i = db0 + t; i < db1; i += 1024) {
    ushort4 r = Dc[i];
    unsigned int pos = atomicAdd(&hist[r.y & (RANGE - 1)], 1u);
    swc[db0 + (int)pos] = make_ushort2(r.x, r.z);
  }
}

// Tx1_i = lhat_i(x) for all convs. 2 rows per wave: 32 lanes x ushort4 per row.
__global__ __launch_bounds__(256) void spmvA(const int* __restrict__ row_ptr,
    const ushort2* __restrict__ srcw, const float* __restrict__ diag,
    const ushort4* __restrict__ xb, ushort4* __restrict__ tx1b, int N, int E, int NCv) {
  int rg = blockIdx.x * 8 + ((int)threadIdx.x >> 5);
  if (rg >= NCv * N) return;
  int conv = rg / N;
  int row = rg - conv * N;
  const int* rp = row_ptr + (size_t)conv * (N + 1);
  const ushort2* sw = srcw + (size_t)conv * E;
  int c4 = threadIdx.x & 31;
  float d = diag[(size_t)conv * N + row];
  ushort4 xv = xb[(size_t)row * 32 + c4];
  float a0 = d * b2f(xv.x), a1 = d * b2f(xv.y);
  float a2 = d * b2f(xv.z), a3 = d * b2f(xv.w);
  int e = rp[row], end = rp[row + 1];
  for (; e + 1 < end; e += 2) {
    ushort2 s0 = sw[e], s1 = sw[e + 1];
    ushort4 v0 = xb[(size_t)s0.x * 32 + c4];
    ushort4 v1 = xb[(size_t)s1.x * 32 + c4];
    float w0 = -b2f(s0.y), w1 = -b2f(s1.y);
    a0 = fmaf(w0, b2f(v0.x), a0); a1 = fmaf(w0, b2f(v0.y), a1);
    a2 = fmaf(w0, b2f(v0.z), a2); a3 = fmaf(w0, b2f(v0.w), a3);
    a0 = fmaf(w1, b2f(v1.x), a0); a1 = fmaf(w1, b2f(v1.y), a1);
    a2 = fmaf(w1, b2f(v1.z), a2); a3 = fmaf(w1, b2f(v1.w), a3);
  }
  if (e < end) {
    ushort2 s0 = sw[e];
    ushort4 v0 = xb[(size_t)s0.x * 32 + c4];
    float w0 = -b2f(s0.y);
    a0 = fmaf(w0, b2f(v0.x), a0); a1 = fmaf(w0, b2f(v0.y), a1);
    a2 = fmaf(w0, b2f(v0.z), a2); a3 = fmaf(w0, b2f(v0.w), a3);
  }
  tx1b[((size_t)conv * N + row) * 32 + c4] =
      make_ushort4(f2b(a0), f2b(a1), f2b(a2), f2b(a3));
}

// Tx2_i = 2*lhat_i(Tx1_i) - x for all convs in one launch
__global__ __launch_bounds__(256) void spmvB_all(const int* __restrict__ row_ptr,
    const ushort2* __restrict__ srcw, const float* __restrict__ diag,
    const ushort4* __restrict__ t1all, const ushort4* __restrict__ xb,
    ushort4* __restrict__ t2all, int N, int E, int NCv) {
  int rg = blockIdx.x * 8 + ((int)threadIdx.x >> 5);
  if (rg >= NCv * N) return;
  int conv = rg / N;
  int row = rg - conv * N;
  const int* rp = row_ptr + (size_t)conv * (N + 1);
  const ushort2* sw = srcw + (size_t)conv * E;
  const ushort4* t1 = t1all + (size_t)conv * N * 32;
  int c4 = threadIdx.x & 31;
  float d = diag[(size_t)conv * N + row];
  ushort4 tv = t1[(size_t)row * 32 + c4];
  float a0 = d * b2f(tv.x), a1 = d * b2f(tv.y);
  float a2 = d * b2f(tv.z), a3 = d * b2f(tv.w);
  int e = rp[row], end = rp[row + 1];
  for (; e + 1 < end; e += 2) {
    ushort2 s0 = sw[e], s1 = sw[e + 1];
    ushort4 v0 = t1[(size_t)s0.x * 32 + c4];
    ushort4 v1 = t1[(size_t)s1.x * 32 + c4];
    float w0 = -b2f(s0.y), w1 = -b2f(s1.y);
    a0 = fmaf(w0, b2f(v0.x), a0); a1 = fmaf(w0, b2f(v0.y), a1);
    a2 = fmaf(w0, b2f(v0.z), a2); a3 = fmaf(w0, b2f(v0.w), a3);
    a0 = fmaf(w1, b2f(v1.x), a0); a1 = fmaf(w1, b2f(v1.y), a1);
    a2 = fmaf(w1, b2f(v1.z), a2); a3 = fmaf(w1, b2f(v1.w), a3);
  }
  if (e < end) {
    ushort2 s0 = sw[e];
    ushort4 v0 = t1[(size_t)s0.x * 32 + c4];
    float w0 = -b2f(s0.y);
    a0 = fmaf(w0, b2f(v0.x), a0); a1 = fmaf(w0, b2f(v0.y), a1);
    a2 = fmaf(w0, b2f(v0.z), a2); a3 = fmaf(w0, b2f(v0.w), a3);
  }
  ushort4 xv = xb[(size_t)row * 32 + c4];
  a0 = 2.f * a0 - b2f(xv.x); a1 = 2.f * a1 - b2f(xv.y);
  a2 = 2.f * a2 - b2f(xv.z); a3 = 2.f * a3 - b2f(xv.w);
  t2all[((size_t)conv * N + row) * 32 + c4] =
      make_ushort4(f2b(a0), f2b(a1), f2b(a2), f2b(a3));
}

// MFMA GEMM: C = bias + Σ_s A_s @ W_s  over 1+2*NCv stages (r6, verified).
__global__ __launch_bounds__(256) void gemm_mfma(const unsigned short* __restrict__ xb,
    const unsigned short* __restrict__ t1all, const unsigned short* __restrict__ t2all,
    const unsigned short* __restrict__ Wtb, const float* __restrict__ bs,
    float* __restrict__ C, int N, int NCv) {
  const int wid = threadIdx.x >> 6;
  const int lane = threadIdx.x & 63;
  const int lr = lane & 15;
  const int lk = lane >> 4;
  const int r0 = blockIdx.x * 64 + wid * 16;
  f32x4 acc[8];
  #pragma unroll
  for (int nt = 0; nt < 8; ++nt) acc[nt] = (f32x4){0.f, 0.f, 0.f, 0.f};

  const int stages = 1 + 2 * NCv;
  int ra = r0 + lr;
  ra = ra < N ? ra : N - 1;
  for (int s = 0; s < stages; ++s) {
    const unsigned short* A;
    if (s == 0) A = xb;
    else if (s & 1) A = t1all + (size_t)((s - 1) >> 1) * N * CDIM;
    else A = t2all + (size_t)((s >> 1) - 1) * N * CDIM;
    const unsigned short* Ap = A + (size_t)ra * CDIM + lk * 8;
    bf16x8 af0 = *(const bf16x8*)(Ap);
    bf16x8 af1 = *(const bf16x8*)(Ap + 32);
    bf16x8 af2 = *(const bf16x8*)(Ap + 64);
    bf16x8 af3 = *(const bf16x8*)(Ap + 96);
    const unsigned short* Wp = Wtb + (size_t)s * CDIM * CDIM + (size_t)lr * CDIM + lk * 8;
    #pragma unroll
    for (int nt = 0; nt < 8; ++nt) {
      const unsigned short* Wn = Wp + nt * 16 * CDIM;
      acc[nt] = __builtin_amdgcn_mfma_f32_16x16x32_bf16(
          af0, *(const bf16x8*)(Wn), acc[nt], 0, 0, 0);
      acc[nt] = __builtin_amdgcn_mfma_f32_16x16x32_bf16(
          af1, *(const bf16x8*)(Wn + 32), acc[nt], 0, 0, 0);
      acc[nt] = __builtin_amdgcn_mfma_f32_16x16x32_bf16(
          af2, *(const bf16x8*)(Wn + 64), acc[nt], 0, 0, 0);
      acc[nt] = __builtin_amdgcn_mfma_f32_16x16x32_bf16(
          af3, *(const bf16x8*)(Wn + 96), acc[nt], 0, 0, 0);
    }
  }
  const int orow = r0 + lk * 4;
  #pragma unroll
  for (int nt = 0; nt < 8; ++nt) {
    int col = nt * 16 + lr;
    float bb = bs[col];
    #pragma unroll
    for (int reg = 0; reg < 4; ++reg) {
      int r = orow + reg;
      if (r < N) C[(size_t)r * CDIM + col] = acc[nt][reg] + bb;
    }
  }
}

extern "C" void kernel_launch(void* const* d_in, const int* in_sizes, int n_in,
                              void* d_out, int out_size, void* d_ws, size_t ws_size,
                              hipStream_t stream) {
  const float* x  = (const float*)d_in[0];
  const int*   ei = (const int*)d_in[1];    // [NC, 2, E] int32
  const float* ew = (const float*)d_in[2];  // [NC, E]
  const float* W  = (const float*)d_in[3];  // [NC, K, 128, 128]
  const float* b  = (const float*)d_in[4];  // [NC, 128]

  const int Nn  = in_sizes[0] / CDIM;
  const int NCv = in_sizes[4] / CDIM;
  const int E   = in_sizes[2] / NCv;
  const int KK  = in_sizes[3] / (NCv * CDIM * CDIM);
  const int stages = 1 + 2 * NCv;
  const int nr = (Nn + RANGE - 1) / RANGE;

  char* p = (char*)d_ws;
  auto take = [&](size_t bytes) { char* q = p; p += (bytes + 255) & ~(size_t)255; return q; };
  float* diag    = (float*)take((size_t)NCv * Nn * 4);
  int*   row_ptr = (int*)take((size_t)NCv * (Nn + 1) * 4);
  int*   coarse  = (int*)take((size_t)NCv * 2 * MAXNR * 4);
  int*   bases_s = (int*)take((size_t)NCv * (MAXNR + 1) * 4);
  int*   bases_d = (int*)take((size_t)NCv * (MAXNR + 1) * 4);
  int*   cur_s   = (int*)take((size_t)NCv * MAXNR * 4);
  int*   cur_d   = (int*)take((size_t)NCv * MAXNR * 4);
  unsigned short* Wtb = (unsigned short*)take((size_t)stages * CDIM * CDIM * 2);
  float* bs      = (float*)take(CDIM * 4);
  ushort2* xb    = (ushort2*)take((size_t)Nn * 64 * 4);
  ushort2* tx1b  = (ushort2*)take((size_t)NCv * Nn * 64 * 4);
  // tx2b region aliased with the transient D/S bucket buffers:
  // D/S are dead after finalize_kernel; tx2b written only by spmvB_all (later).
  size_t D_bytes  = ((size_t)NCv * E * 8 + 255) & ~(size_t)255;
  size_t S_bytes  = ((size_t)NCv * E * 4 + 255) & ~(size_t)255;
  size_t tx2_bytes = (size_t)NCv * Nn * 64 * 4;
  size_t big_bytes = D_bytes + S_bytes > tx2_bytes ? D_bytes + S_bytes : tx2_bytes;
  char* big = take(big_bytes);
  ushort2* tx2b = (ushort2*)big;
  ushort4* D    = (ushort4*)big;
  ushort2* S    = (ushort2*)(big + D_bytes);
  ushort2* srcw = (ushort2*)take((size_t)NCv * E * 4);

  hipMemsetAsync(coarse, 0, (size_t)NCv * 2 * MAXNR * 4, stream);

  xcast_kernel<<<(Nn * 64 + 255) / 256, 256, 0, stream>>>(
      (const float2*)x, xb, Nn * 64);
  wcast_kernel<<<(stages * CDIM * CDIM + 255) / 256, 256, 0, stream>>>(
      W, b, Wtb, bs, KK, NCv);
  hist_coarse<<<512, 256, 0, stream>>>(ei, coarse, E, NCv, nr);
  scan_coarse<<<1, 64, 0, stream>>>(coarse, bases_s, bases_d, cur_s, cur_d, NCv, nr);

  const int P = 256;
  const int CE = (E + P - 1) / P;
  partition_kernel<<<NCv * P, 256, 0, stream>>>(ei, ew, cur_d, cur_s, D, S,
                                                E, CE, P, NCv, nr);
  finalize_kernel<<<NCv * nr, 1024, 0, stream>>>(D, S, bases_d, bases_s,
                                                 row_ptr, diag, srcw, E, Nn, NCv, nr);

  spmvA<<<(NCv * Nn + 7) / 8, 256, 0, stream>>>(row_ptr, srcw, diag,
      (const ushort4*)xb, (ushort4*)tx1b, Nn, E, NCv);
  spmvB_all<<<(NCv * Nn + 7) / 8, 256, 0, stream>>>(row_ptr, srcw, diag,
      (const ushort4*)tx1b, (const ushort4*)xb, (ushort4*)tx2b, Nn, E, NCv);

  gemm_mfma<<<(Nn + 63) / 64, 256, 0, stream>>>(
      (const unsigned short*)xb, (const unsigned short*)tx1b,
      (const unsigned short*)tx2b, Wtb, bs, (float*)d_out, Nn, NCv);
}

// Round 8
// 442.520 us; speedup vs baseline: 2.0906x; 1.2352x over previous
//
#include <hip/hip_runtime.h>

// out = Σ_i ChebConv_i(x), K=3, normalization=None, lambda_max=2 (scale=1).
// lhat(v)[r] = (deg[r]-1)*v[r] - Σ_{e:dst=r} w_e v[src_e]
// Tx1 = lhat(x); Tx2 = 2*lhat(Tx1) - x
// out = x@ΣW[i,0] + Σ_i (Tx1_i@W[i,1] + Tx2_i@W[i,2]) + Σ_i b_i
//
// Round 8: finalize was 179us at 6% occupancy (grid=39 blocks, latency-bound
// streaming). Shrink buckets RANGE 4096->512: finalize grid 39->294 blocks of
// 512 threads, LDS 33KB->4.2KB. Radix structure otherwise unchanged.

#define CDIM 128
#define RANGE 512
#define RSH 9
#define MAXNR 128

typedef __attribute__((ext_vector_type(8))) short bf16x8;
typedef __attribute__((ext_vector_type(4))) float f32x4;

__device__ __forceinline__ float b2f(unsigned short h) {
  return __uint_as_float((unsigned)h << 16);
}
__device__ __forceinline__ unsigned short f2b(float f) {
  unsigned u = __float_as_uint(f);
  return (unsigned short)((u + 0x7FFF + ((u >> 16) & 1)) >> 16);
}

// x (f32) -> xb (bf16 pairs)
__global__ __launch_bounds__(256) void xcast_kernel(const float2* __restrict__ x,
    ushort2* __restrict__ xb, int total2) {
  int i = blockIdx.x * 256 + threadIdx.x;
  if (i >= total2) return;
  float2 v = x[i];
  xb[i] = make_ushort2(f2b(v.x), f2b(v.y));
}

// Wtb[s][n][k] (bf16, transposed weights) for the 1+2*NCv GEMM stages; bs = Σ b_i.
__global__ __launch_bounds__(256) void wcast_kernel(const float* __restrict__ W,
    const float* __restrict__ b, unsigned short* __restrict__ Wtb,
    float* __restrict__ bs, int KK, int NCv) {
  int p = blockIdx.x * 256 + threadIdx.x;
  const int stages = 1 + 2 * NCv;
  if (p < stages * CDIM * CDIM) {
    int s = p >> 14;
    int nk = p & 16383;
    int n = nk >> 7, k = nk & 127;
    float v;
    if (s == 0) {
      v = 0.f;
      for (int i = 0; i < NCv; ++i)
        v += W[(size_t)i * KK * CDIM * CDIM + (size_t)k * CDIM + n];
    } else {
      int i, kk;
      if (s & 1) { i = (s - 1) >> 1; kk = 1; }
      else       { i = (s >> 1) - 1; kk = 2; }
      v = W[(size_t)i * KK * CDIM * CDIM + (size_t)kk * CDIM * CDIM + (size_t)k * CDIM + n];
    }
    Wtb[p] = f2b(v);
  }
  if (p < CDIM) {
    float s = 0.f;
    for (int i = 0; i < NCv; ++i) s += b[i * CDIM + p];
    bs[p] = s;
  }
}

// coarse per-bucket counts of src and dst, LDS-aggregated
// coarse layout: [conv][2][MAXNR]  (axis 0 = src, 1 = dst)
__global__ __launch_bounds__(256) void hist_coarse(const int* __restrict__ ei,
    int* __restrict__ coarse, int E, int NCv, int nr) {
  __shared__ int h[2 * MAXNR];
  int t = threadIdx.x;
  int g0 = blockIdx.x * 256 + t;
  int stride = gridDim.x * 256;
  for (int conv = 0; conv < NCv; ++conv) {
    if (t < 2 * MAXNR) h[t] = 0;
    __syncthreads();
    const int* srcv = ei + (size_t)conv * 2 * E;
    const int* dstv = srcv + E;
    for (int e = g0; e < E; e += stride) {
      atomicAdd(&h[srcv[e] >> RSH], 1);
      atomicAdd(&h[MAXNR + (dstv[e] >> RSH)], 1);
    }
    __syncthreads();
    if (t < nr) {
      if (h[t]) atomicAdd(&coarse[(conv * 2 + 0) * MAXNR + t], h[t]);
      if (h[MAXNR + t]) atomicAdd(&coarse[(conv * 2 + 1) * MAXNR + t], h[MAXNR + t]);
    }
    __syncthreads();
  }
}

// tiny serial scans: bases_d/s[conv][0..nr], cursors init = bases
__global__ __launch_bounds__(64) void scan_coarse(const int* __restrict__ coarse,
    int* __restrict__ bases_s, int* __restrict__ bases_d,
    int* __restrict__ cur_s, int* __restrict__ cur_d, int NCv, int nr) {
  int t = threadIdx.x;
  if (t >= NCv * 2) return;
  int conv = t >> 1, ax = t & 1;
  const int* c = coarse + (conv * 2 + ax) * MAXNR;
  int* bases = (ax ? bases_d : bases_s) + conv * (MAXNR + 1);
  int* cur = (ax ? cur_d : cur_s) + conv * MAXNR;
  int acc = 0;
  for (int b = 0; b < nr; ++b) {
    bases[b] = acc; cur[b] = acc; acc += c[b];
  }
  bases[nr] = acc;
}

// partition edges into node-range buckets. Per block: LDS count -> one global
// atomic per bucket to grab a contiguous run -> LDS-cursor placement.
// D record (dst-bucketed): (src u16, dst u16, w bf16, 0). S record: (src u16, w bf16).
__global__ __launch_bounds__(256) void partition_kernel(const int* __restrict__ ei,
    const float* __restrict__ ew, int* __restrict__ cur_d, int* __restrict__ cur_s,
    ushort4* __restrict__ D, ushort2* __restrict__ S, int E, int CE, int P,
    int NCv, int nr) {
  __shared__ int ld[MAXNR], ls[MAXNR], cd[MAXNR], cs[MAXNR];
  int conv = blockIdx.x / P;
  int pck = blockIdx.x - conv * P;
  int e0 = pck * CE;
  int e1 = min(E, e0 + CE);
  int t = threadIdx.x;
  const int* srcv = ei + (size_t)conv * 2 * E;
  const int* dstv = srcv + E;
  const float* w = ew + (size_t)conv * E;
  if (t < MAXNR) { ld[t] = 0; ls[t] = 0; }
  __syncthreads();
  for (int e = e0 + t; e < e1; e += 256) {
    atomicAdd(&ld[dstv[e] >> RSH], 1);
    atomicAdd(&ls[srcv[e] >> RSH], 1);
  }
  __syncthreads();
  if (t < nr) {
    cd[t] = ld[t] ? atomicAdd(&cur_d[conv * MAXNR + t], ld[t]) : 0;
    cs[t] = ls[t] ? atomicAdd(&cur_s[conv * MAXNR + t], ls[t]) : 0;
  }
  __syncthreads();
  ushort4* Dc = D + (size_t)conv * E;
  ushort2* Sc = S + (size_t)conv * E;
  for (int e = e0 + t; e < e1; e += 256) {
    int s = srcv[e], d = dstv[e];
    unsigned short wb = f2b(w[e]);
    int pd = atomicAdd(&cd[d >> RSH], 1);
    Dc[pd] = make_ushort4((unsigned short)s, (unsigned short)d, wb, 0);
    int ps = atomicAdd(&cs[s >> RSH], 1);
    Sc[ps] = make_ushort2((unsigned short)s, wb);
  }
}

// per (conv, bucket): LDS fine hist of dst + float deg of src; block scan;
// write row_ptr & diag; place CSR records via LDS cursors. No global atomics.
// 512 threads, one bin per thread for the scan.
__global__ __launch_bounds__(512) void finalize_kernel(const ushort4* __restrict__ D,
    const ushort2* __restrict__ S, const int* __restrict__ bases_d,
    const int* __restrict__ bases_s, int* __restrict__ row_ptr,
    float* __restrict__ diag, ushort2* __restrict__ srcw, int E, int N,
    int NCv, int nr) {
  __shared__ unsigned int hist[RANGE];
  __shared__ float fdeg[RANGE];
  __shared__ unsigned int wls[8];
  int conv = blockIdx.x / nr;
  int b = blockIdx.x - conv * nr;
  int t = threadIdx.x;
  hist[t] = 0u; fdeg[t] = 0.f;
  __syncthreads();
  int db0 = bases_d[conv * (MAXNR + 1) + b], db1 = bases_d[conv * (MAXNR + 1) + b + 1];
  int sb0 = bases_s[conv * (MAXNR + 1) + b], sb1 = bases_s[conv * (MAXNR + 1) + b + 1];
  const ushort4* Dc = D + (size_t)conv * E;
  const ushort2* Sc = S + (size_t)conv * E;
  for (int i = db0 + t; i < db1; i += 512)
    atomicAdd(&hist[Dc[i].y & (RANGE - 1)], 1u);
  for (int i = sb0 + t; i < sb1; i += 512) {
    ushort2 r = Sc[i];
    atomicAdd(&fdeg[r.x & (RANGE - 1)], b2f(r.y));
  }
  __syncthreads();
  // block exclusive scan over 512 bins, one per thread
  unsigned int v = hist[t];
  int lane = t & 63, wid = t >> 6;
  unsigned int incl = v;
  #pragma unroll
  for (int off = 1; off < 64; off <<= 1) {
    unsigned int tmp = __shfl_up((int)incl, off, 64);
    if (lane >= off) incl += tmp;
  }
  if (lane == 63) wls[wid] = incl;
  __syncthreads();
  if (wid == 0) {
    unsigned int x = (lane < 8) ? wls[lane] : 0u;
    #pragma unroll
    for (int off = 1; off < 8; off <<= 1) {
      unsigned int tmp = __shfl_up((int)x, off, 64);
      if (lane >= off) x += tmp;
    }
    if (lane < 8) wls[lane] = x;
  }
  __syncthreads();
  unsigned int excl = (wid ? wls[wid - 1] : 0u) + (incl - v);
  hist[t] = excl;
  __syncthreads();
  // row_ptr (positions within conv's CSR segment) + diag
  int n0 = b << RSH;
  int* rp = row_ptr + (size_t)conv * (N + 1);
  float* dg = diag + (size_t)conv * N;
  int n = n0 + t;
  if (n < N) {
    rp[n] = db0 + (int)excl;
    dg[n] = fdeg[t] - 1.0f;
  }
  if (b == nr - 1 && t == 0) rp[N] = E;
  __syncthreads();
  // place records (hist now serves as cursors)
  ushort2* swc = srcw + (size_t)conv * E;
  for (int i = db0 + t; i < db1; i += 512) {
    ushort4 r = Dc[i];
    unsigned int pos = atomicAdd(&hist[r.y & (RANGE - 1)], 1u);
    swc[db0 + (int)pos] = make_ushort2(r.x, r.z);
  }
}

// Tx1_i = lhat_i(x) for all convs. 2 rows per wave: 32 lanes x ushort4 per row.
__global__ __launch_bounds__(256) void spmvA(const int* __restrict__ row_ptr,
    const ushort2* __restrict__ srcw, const float* __restrict__ diag,
    const ushort4* __restrict__ xb, ushort4* __restrict__ tx1b, int N, int E, int NCv) {
  int rg = blockIdx.x * 8 + ((int)threadIdx.x >> 5);
  if (rg >= NCv * N) return;
  int conv = rg / N;
  int row = rg - conv * N;
  const int* rp = row_ptr + (size_t)conv * (N + 1);
  const ushort2* sw = srcw + (size_t)conv * E;
  int c4 = threadIdx.x & 31;
  float d = diag[(size_t)conv * N + row];
  ushort4 xv = xb[(size_t)row * 32 + c4];
  float a0 = d * b2f(xv.x), a1 = d * b2f(xv.y);
  float a2 = d * b2f(xv.z), a3 = d * b2f(xv.w);
  int e = rp[row], end = rp[row + 1];
  for (; e + 1 < end; e += 2) {
    ushort2 s0 = sw[e], s1 = sw[e + 1];
    ushort4 v0 = xb[(size_t)s0.x * 32 + c4];
    ushort4 v1 = xb[(size_t)s1.x * 32 + c4];
    float w0 = -b2f(s0.y), w1 = -b2f(s1.y);
    a0 = fmaf(w0, b2f(v0.x), a0); a1 = fmaf(w0, b2f(v0.y), a1);
    a2 = fmaf(w0, b2f(v0.z), a2); a3 = fmaf(w0, b2f(v0.w), a3);
    a0 = fmaf(w1, b2f(v1.x), a0); a1 = fmaf(w1, b2f(v1.y), a1);
    a2 = fmaf(w1, b2f(v1.z), a2); a3 = fmaf(w1, b2f(v1.w), a3);
  }
  if (e < end) {
    ushort2 s0 = sw[e];
    ushort4 v0 = xb[(size_t)s0.x * 32 + c4];
    float w0 = -b2f(s0.y);
    a0 = fmaf(w0, b2f(v0.x), a0); a1 = fmaf(w0, b2f(v0.y), a1);
    a2 = fmaf(w0, b2f(v0.z), a2); a3 = fmaf(w0, b2f(v0.w), a3);
  }
  tx1b[((size_t)conv * N + row) * 32 + c4] =
      make_ushort4(f2b(a0), f2b(a1), f2b(a2), f2b(a3));
}

// Tx2_i = 2*lhat_i(Tx1_i) - x for all convs in one launch
__global__ __launch_bounds__(256) void spmvB_all(const int* __restrict__ row_ptr,
    const ushort2* __restrict__ srcw, const float* __restrict__ diag,
    const ushort4* __restrict__ t1all, const ushort4* __restrict__ xb,
    ushort4* __restrict__ t2all, int N, int E, int NCv) {
  int rg = blockIdx.x * 8 + ((int)threadIdx.x >> 5);
  if (rg >= NCv * N) return;
  int conv = rg / N;
  int row = rg - conv * N;
  const int* rp = row_ptr + (size_t)conv * (N + 1);
  const ushort2* sw = srcw + (size_t)conv * E;
  const ushort4* t1 = t1all + (size_t)conv * N * 32;
  int c4 = threadIdx.x & 31;
  float d = diag[(size_t)conv * N + row];
  ushort4 tv = t1[(size_t)row * 32 + c4];
  float a0 = d * b2f(tv.x), a1 = d * b2f(tv.y);
  float a2 = d * b2f(tv.z), a3 = d * b2f(tv.w);
  int e = rp[row], end = rp[row + 1];
  for (; e + 1 < end; e += 2) {
    ushort2 s0 = sw[e], s1 = sw[e + 1];
    ushort4 v0 = t1[(size_t)s0.x * 32 + c4];
    ushort4 v1 = t1[(size_t)s1.x * 32 + c4];
    float w0 = -b2f(s0.y), w1 = -b2f(s1.y);
    a0 = fmaf(w0, b2f(v0.x), a0); a1 = fmaf(w0, b2f(v0.y), a1);
    a2 = fmaf(w0, b2f(v0.z), a2); a3 = fmaf(w0, b2f(v0.w), a3);
    a0 = fmaf(w1, b2f(v1.x), a0); a1 = fmaf(w1, b2f(v1.y), a1);
    a2 = fmaf(w1, b2f(v1.z), a2); a3 = fmaf(w1, b2f(v1.w), a3);
  }
  if (e < end) {
    ushort2 s0 = sw[e];
    ushort4 v0 = t1[(size_t)s0.x * 32 + c4];
    float w0 = -b2f(s0.y);
    a0 = fmaf(w0, b2f(v0.x), a0); a1 = fmaf(w0, b2f(v0.y), a1);
    a2 = fmaf(w0, b2f(v0.z), a2); a3 = fmaf(w0, b2f(v0.w), a3);
  }
  ushort4 xv = xb[(size_t)row * 32 + c4];
  a0 = 2.f * a0 - b2f(xv.x); a1 = 2.f * a1 - b2f(xv.y);
  a2 = 2.f * a2 - b2f(xv.z); a3 = 2.f * a3 - b2f(xv.w);
  t2all[((size_t)conv * N + row) * 32 + c4] =
      make_ushort4(f2b(a0), f2b(a1), f2b(a2), f2b(a3));
}

// MFMA GEMM: C = bias + Σ_s A_s @ W_s  over 1+2*NCv stages (r6, verified).
__global__ __launch_bounds__(256) void gemm_mfma(const unsigned short* __restrict__ xb,
    const unsigned short* __restrict__ t1all, const unsigned short* __restrict__ t2all,
    const unsigned short* __restrict__ Wtb, const float* __restrict__ bs,
    float* __restrict__ C, int N, int NCv) {
  const int wid = threadIdx.x >> 6;
  const int lane = threadIdx.x & 63;
  const int lr = lane & 15;
  const int lk = lane >> 4;
  const int r0 = blockIdx.x * 64 + wid * 16;
  f32x4 acc[8];
  #pragma unroll
  for (int nt = 0; nt < 8; ++nt) acc[nt] = (f32x4){0.f, 0.f, 0.f, 0.f};

  const int stages = 1 + 2 * NCv;
  int ra = r0 + lr;
  ra = ra < N ? ra : N - 1;
  for (int s = 0; s < stages; ++s) {
    const unsigned short* A;
    if (s == 0) A = xb;
    else if (s & 1) A = t1all + (size_t)((s - 1) >> 1) * N * CDIM;
    else A = t2all + (size_t)((s >> 1) - 1) * N * CDIM;
    const unsigned short* Ap = A + (size_t)ra * CDIM + lk * 8;
    bf16x8 af0 = *(const bf16x8*)(Ap);
    bf16x8 af1 = *(const bf16x8*)(Ap + 32);
    bf16x8 af2 = *(const bf16x8*)(Ap + 64);
    bf16x8 af3 = *(const bf16x8*)(Ap + 96);
    const unsigned short* Wp = Wtb + (size_t)s * CDIM * CDIM + (size_t)lr * CDIM + lk * 8;
    #pragma unroll
    for (int nt = 0; nt < 8; ++nt) {
      const unsigned short* Wn = Wp + nt * 16 * CDIM;
      acc[nt] = __builtin_amdgcn_mfma_f32_16x16x32_bf16(
          af0, *(const bf16x8*)(Wn), acc[nt], 0, 0, 0);
      acc[nt] = __builtin_amdgcn_mfma_f32_16x16x32_bf16(
          af1, *(const bf16x8*)(Wn + 32), acc[nt], 0, 0, 0);
      acc[nt] = __builtin_amdgcn_mfma_f32_16x16x32_bf16(
          af2, *(const bf16x8*)(Wn + 64), acc[nt], 0, 0, 0);
      acc[nt] = __builtin_amdgcn_mfma_f32_16x16x32_bf16(
          af3, *(const bf16x8*)(Wn + 96), acc[nt], 0, 0, 0);
    }
  }
  const int orow = r0 + lk * 4;
  #pragma unroll
  for (int nt = 0; nt < 8; ++nt) {
    int col = nt * 16 + lr;
    float bb = bs[col];
    #pragma unroll
    for (int reg = 0; reg < 4; ++reg) {
      int r = orow + reg;
      if (r < N) C[(size_t)r * CDIM + col] = acc[nt][reg] + bb;
    }
  }
}

extern "C" void kernel_launch(void* const* d_in, const int* in_sizes, int n_in,
                              void* d_out, int out_size, void* d_ws, size_t ws_size,
                              hipStream_t stream) {
  const float* x  = (const float*)d_in[0];
  const int*   ei = (const int*)d_in[1];    // [NC, 2, E] int32
  const float* ew = (const float*)d_in[2];  // [NC, E]
  const float* W  = (const float*)d_in[3];  // [NC, K, 128, 128]
  const float* b  = (const float*)d_in[4];  // [NC, 128]

  const int Nn  = in_sizes[0] / CDIM;
  const int NCv = in_sizes[4] / CDIM;
  const int E   = in_sizes[2] / NCv;
  const int KK  = in_sizes[3] / (NCv * CDIM * CDIM);
  const int stages = 1 + 2 * NCv;
  const int nr = (Nn + RANGE - 1) / RANGE;

  char* p = (char*)d_ws;
  auto take = [&](size_t bytes) { char* q = p; p += (bytes + 255) & ~(size_t)255; return q; };
  float* diag    = (float*)take((size_t)NCv * Nn * 4);
  int*   row_ptr = (int*)take((size_t)NCv * (Nn + 1) * 4);
  int*   coarse  = (int*)take((size_t)NCv * 2 * MAXNR * 4);
  int*   bases_s = (int*)take((size_t)NCv * (MAXNR + 1) * 4);
  int*   bases_d = (int*)take((size_t)NCv * (MAXNR + 1) * 4);
  int*   cur_s   = (int*)take((size_t)NCv * MAXNR * 4);
  int*   cur_d   = (int*)take((size_t)NCv * MAXNR * 4);
  unsigned short* Wtb = (unsigned short*)take((size_t)stages * CDIM * CDIM * 2);
  float* bs      = (float*)take(CDIM * 4);
  ushort2* xb    = (ushort2*)take((size_t)Nn * 64 * 4);
  ushort2* tx1b  = (ushort2*)take((size_t)NCv * Nn * 64 * 4);
  // tx2b region aliased with the transient D/S bucket buffers:
  // D/S are dead after finalize_kernel; tx2b written only by spmvB_all (later).
  size_t D_bytes  = ((size_t)NCv * E * 8 + 255) & ~(size_t)255;
  size_t S_bytes  = ((size_t)NCv * E * 4 + 255) & ~(size_t)255;
  size_t tx2_bytes = (size_t)NCv * Nn * 64 * 4;
  size_t big_bytes = D_bytes + S_bytes > tx2_bytes ? D_bytes + S_bytes : tx2_bytes;
  char* big = take(big_bytes);
  ushort2* tx2b = (ushort2*)big;
  ushort4* D    = (ushort4*)big;
  ushort2* S    = (ushort2*)(big + D_bytes);
  ushort2* srcw = (ushort2*)take((size_t)NCv * E * 4);

  hipMemsetAsync(coarse, 0, (size_t)NCv * 2 * MAXNR * 4, stream);

  xcast_kernel<<<(Nn * 64 + 255) / 256, 256, 0, stream>>>(
      (const float2*)x, xb, Nn * 64);
  wcast_kernel<<<(stages * CDIM * CDIM + 255) / 256, 256, 0, stream>>>(
      W, b, Wtb, bs, KK, NCv);
  hist_coarse<<<512, 256, 0, stream>>>(ei, coarse, E, NCv, nr);
  scan_coarse<<<1, 64, 0, stream>>>(coarse, bases_s, bases_d, cur_s, cur_d, NCv, nr);

  const int P = 256;
  const int CE = (E + P - 1) / P;
  partition_kernel<<<NCv * P, 256, 0, stream>>>(ei, ew, cur_d, cur_s, D, S,
                                                E, CE, P, NCv, nr);
  finalize_kernel<<<NCv * nr, 512, 0, stream>>>(D, S, bases_d, bases_s,
                                                row_ptr, diag, srcw, E, Nn, NCv, nr);

  spmvA<<<(NCv * Nn + 7) / 8, 256, 0, stream>>>(row_ptr, srcw, diag,
      (const ushort4*)xb, (ushort4*)tx1b, Nn, E, NCv);
  spmvB_all<<<(NCv * Nn + 7) / 8, 256, 0, stream>>>(row_ptr, srcw, diag,
      (const ushort4*)tx1b, (const ushort4*)xb, (ushort4*)tx2b, Nn, E, NCv);

  gemm_mfma<<<(Nn + 63) / 64, 256, 0, stream>>>(
      (const unsigned short*)xb, (const unsigned short*)tx1b,
      (const unsigned short*)tx2b, Wtb, bs, (float*)d_out, Nn, NCv);
}

// Round 9
// 338.543 us; speedup vs baseline: 2.7327x; 1.3071x over previous
//
#include <hip/hip_runtime.h>

// out = Σ_i ChebConv_i(x), K=3, normalization=None, lambda_max=2 (scale=1).
// lhat(v)[r] = (deg[r]-1)*v[r] - Σ_{e:dst=r} w_e v[src_e]
// Tx1 = lhat(x); Tx2 = 2*lhat(Tx1) - x
// out = x@ΣW[i,0] + Σ_i (Tx1_i@W[i,1] + Tx2_i@W[i,2]) + Σ_i b_i
//
// Round 9: gemm_mfma was 120us, MfmaUtil 3.6% -> B-loads from global on the
// MFMA critical path (latency-bound). Stage B per-stage in LDS (double-buffer,
// reg-staged issue-early/write-late, 1 barrier/stage), XOR-swizzled
// (byte ^= (row&7)<<4) for conflict-free ds_read_b128. Prefetch A-frags one
// stage ahead. spmv edge loop unroll 2->4.

#define CDIM 128
#define RANGE 512
#define RSH 9
#define MAXNR 128

typedef __attribute__((ext_vector_type(8))) short bf16x8;
typedef __attribute__((ext_vector_type(8))) unsigned short u16x8;
typedef __attribute__((ext_vector_type(4))) float f32x4;

__device__ __forceinline__ float b2f(unsigned short h) {
  return __uint_as_float((unsigned)h << 16);
}
__device__ __forceinline__ unsigned short f2b(float f) {
  unsigned u = __float_as_uint(f);
  return (unsigned short)((u + 0x7FFF + ((u >> 16) & 1)) >> 16);
}

// x (f32) -> xb (bf16 pairs)
__global__ __launch_bounds__(256) void xcast_kernel(const float2* __restrict__ x,
    ushort2* __restrict__ xb, int total2) {
  int i = blockIdx.x * 256 + threadIdx.x;
  if (i >= total2) return;
  float2 v = x[i];
  xb[i] = make_ushort2(f2b(v.x), f2b(v.y));
}

// Wtb[s][n][k] (bf16, transposed weights) for the 1+2*NCv GEMM stages; bs = Σ b_i.
__global__ __launch_bounds__(256) void wcast_kernel(const float* __restrict__ W,
    const float* __restrict__ b, unsigned short* __restrict__ Wtb,
    float* __restrict__ bs, int KK, int NCv) {
  int p = blockIdx.x * 256 + threadIdx.x;
  const int stages = 1 + 2 * NCv;
  if (p < stages * CDIM * CDIM) {
    int s = p >> 14;
    int nk = p & 16383;
    int n = nk >> 7, k = nk & 127;
    float v;
    if (s == 0) {
      v = 0.f;
      for (int i = 0; i < NCv; ++i)
        v += W[(size_t)i * KK * CDIM * CDIM + (size_t)k * CDIM + n];
    } else {
      int i, kk;
      if (s & 1) { i = (s - 1) >> 1; kk = 1; }
      else       { i = (s >> 1) - 1; kk = 2; }
      v = W[(size_t)i * KK * CDIM * CDIM + (size_t)kk * CDIM * CDIM + (size_t)k * CDIM + n];
    }
    Wtb[p] = f2b(v);
  }
  if (p < CDIM) {
    float s = 0.f;
    for (int i = 0; i < NCv; ++i) s += b[i * CDIM + p];
    bs[p] = s;
  }
}

// coarse per-bucket counts of src and dst, LDS-aggregated
__global__ __launch_bounds__(256) void hist_coarse(const int* __restrict__ ei,
    int* __restrict__ coarse, int E, int NCv, int nr) {
  __shared__ int h[2 * MAXNR];
  int t = threadIdx.x;
  int g0 = blockIdx.x * 256 + t;
  int stride = gridDim.x * 256;
  for (int conv = 0; conv < NCv; ++conv) {
    if (t < 2 * MAXNR) h[t] = 0;
    __syncthreads();
    const int* srcv = ei + (size_t)conv * 2 * E;
    const int* dstv = srcv + E;
    for (int e = g0; e < E; e += stride) {
      atomicAdd(&h[srcv[e] >> RSH], 1);
      atomicAdd(&h[MAXNR + (dstv[e] >> RSH)], 1);
    }
    __syncthreads();
    if (t < nr) {
      if (h[t]) atomicAdd(&coarse[(conv * 2 + 0) * MAXNR + t], h[t]);
      if (h[MAXNR + t]) atomicAdd(&coarse[(conv * 2 + 1) * MAXNR + t], h[MAXNR + t]);
    }
    __syncthreads();
  }
}

// tiny serial scans: bases_d/s[conv][0..nr], cursors init = bases
__global__ __launch_bounds__(64) void scan_coarse(const int* __restrict__ coarse,
    int* __restrict__ bases_s, int* __restrict__ bases_d,
    int* __restrict__ cur_s, int* __restrict__ cur_d, int NCv, int nr) {
  int t = threadIdx.x;
  if (t >= NCv * 2) return;
  int conv = t >> 1, ax = t & 1;
  const int* c = coarse + (conv * 2 + ax) * MAXNR;
  int* bases = (ax ? bases_d : bases_s) + conv * (MAXNR + 1);
  int* cur = (ax ? cur_d : cur_s) + conv * MAXNR;
  int acc = 0;
  for (int b = 0; b < nr; ++b) {
    bases[b] = acc; cur[b] = acc; acc += c[b];
  }
  bases[nr] = acc;
}

// partition edges into node-range buckets (see r7/r8)
__global__ __launch_bounds__(256) void partition_kernel(const int* __restrict__ ei,
    const float* __restrict__ ew, int* __restrict__ cur_d, int* __restrict__ cur_s,
    ushort4* __restrict__ D, ushort2* __restrict__ S, int E, int CE, int P,
    int NCv, int nr) {
  __shared__ int ld[MAXNR], ls[MAXNR], cd[MAXNR], cs[MAXNR];
  int conv = blockIdx.x / P;
  int pck = blockIdx.x - conv * P;
  int e0 = pck * CE;
  int e1 = min(E, e0 + CE);
  int t = threadIdx.x;
  const int* srcv = ei + (size_t)conv * 2 * E;
  const int* dstv = srcv + E;
  const float* w = ew + (size_t)conv * E;
  if (t < MAXNR) { ld[t] = 0; ls[t] = 0; }
  __syncthreads();
  for (int e = e0 + t; e < e1; e += 256) {
    atomicAdd(&ld[dstv[e] >> RSH], 1);
    atomicAdd(&ls[srcv[e] >> RSH], 1);
  }
  __syncthreads();
  if (t < nr) {
    cd[t] = ld[t] ? atomicAdd(&cur_d[conv * MAXNR + t], ld[t]) : 0;
    cs[t] = ls[t] ? atomicAdd(&cur_s[conv * MAXNR + t], ls[t]) : 0;
  }
  __syncthreads();
  ushort4* Dc = D + (size_t)conv * E;
  ushort2* Sc = S + (size_t)conv * E;
  for (int e = e0 + t; e < e1; e += 256) {
    int s = srcv[e], d = dstv[e];
    unsigned short wb = f2b(w[e]);
    int pd = atomicAdd(&cd[d >> RSH], 1);
    Dc[pd] = make_ushort4((unsigned short)s, (unsigned short)d, wb, 0);
    int ps = atomicAdd(&cs[s >> RSH], 1);
    Sc[ps] = make_ushort2((unsigned short)s, wb);
  }
}

// per (conv, bucket): LDS fine hist + deg; block scan; write row_ptr/diag/CSR.
__global__ __launch_bounds__(512) void finalize_kernel(const ushort4* __restrict__ D,
    const ushort2* __restrict__ S, const int* __restrict__ bases_d,
    const int* __restrict__ bases_s, int* __restrict__ row_ptr,
    float* __restrict__ diag, ushort2* __restrict__ srcw, int E, int N,
    int NCv, int nr) {
  __shared__ unsigned int hist[RANGE];
  __shared__ float fdeg[RANGE];
  __shared__ unsigned int wls[8];
  int conv = blockIdx.x / nr;
  int b = blockIdx.x - conv * nr;
  int t = threadIdx.x;
  hist[t] = 0u; fdeg[t] = 0.f;
  __syncthreads();
  int db0 = bases_d[conv * (MAXNR + 1) + b], db1 = bases_d[conv * (MAXNR + 1) + b + 1];
  int sb0 = bases_s[conv * (MAXNR + 1) + b], sb1 = bases_s[conv * (MAXNR + 1) + b + 1];
  const ushort4* Dc = D + (size_t)conv * E;
  const ushort2* Sc = S + (size_t)conv * E;
  for (int i = db0 + t; i < db1; i += 512)
    atomicAdd(&hist[Dc[i].y & (RANGE - 1)], 1u);
  for (int i = sb0 + t; i < sb1; i += 512) {
    ushort2 r = Sc[i];
    atomicAdd(&fdeg[r.x & (RANGE - 1)], b2f(r.y));
  }
  __syncthreads();
  unsigned int v = hist[t];
  int lane = t & 63, wid = t >> 6;
  unsigned int incl = v;
  #pragma unroll
  for (int off = 1; off < 64; off <<= 1) {
    unsigned int tmp = __shfl_up((int)incl, off, 64);
    if (lane >= off) incl += tmp;
  }
  if (lane == 63) wls[wid] = incl;
  __syncthreads();
  if (wid == 0) {
    unsigned int x = (lane < 8) ? wls[lane] : 0u;
    #pragma unroll
    for (int off = 1; off < 8; off <<= 1) {
      unsigned int tmp = __shfl_up((int)x, off, 64);
      if (lane >= off) x += tmp;
    }
    if (lane < 8) wls[lane] = x;
  }
  __syncthreads();
  unsigned int excl = (wid ? wls[wid - 1] : 0u) + (incl - v);
  hist[t] = excl;
  __syncthreads();
  int n0 = b << RSH;
  int* rp = row_ptr + (size_t)conv * (N + 1);
  float* dg = diag + (size_t)conv * N;
  int n = n0 + t;
  if (n < N) {
    rp[n] = db0 + (int)excl;
    dg[n] = fdeg[t] - 1.0f;
  }
  if (b == nr - 1 && t == 0) rp[N] = E;
  __syncthreads();
  ushort2* swc = srcw + (size_t)conv * E;
  for (int i = db0 + t; i < db1; i += 512) {
    ushort4 r = Dc[i];
    unsigned int pos = atomicAdd(&hist[r.y & (RANGE - 1)], 1u);
    swc[db0 + (int)pos] = make_ushort2(r.x, r.z);
  }
}

// Tx1_i = lhat_i(x), all convs. 2 rows/wave, 4-edge unroll.
__global__ __launch_bounds__(256) void spmvA(const int* __restrict__ row_ptr,
    const ushort2* __restrict__ srcw, const float* __restrict__ diag,
    const ushort4* __restrict__ xb, ushort4* __restrict__ tx1b, int N, int E, int NCv) {
  int rg = blockIdx.x * 8 + ((int)threadIdx.x >> 5);
  if (rg >= NCv * N) return;
  int conv = rg / N;
  int row = rg - conv * N;
  const int* rp = row_ptr + (size_t)conv * (N + 1);
  const ushort2* sw = srcw + (size_t)conv * E;
  int c4 = threadIdx.x & 31;
  float d = diag[(size_t)conv * N + row];
  ushort4 xv = xb[(size_t)row * 32 + c4];
  float a0 = d * b2f(xv.x), a1 = d * b2f(xv.y);
  float a2 = d * b2f(xv.z), a3 = d * b2f(xv.w);
  int e = rp[row], end = rp[row + 1];
  for (; e + 3 < end; e += 4) {
    ushort2 s0 = sw[e], s1 = sw[e + 1], s2 = sw[e + 2], s3 = sw[e + 3];
    ushort4 v0 = xb[(size_t)s0.x * 32 + c4];
    ushort4 v1 = xb[(size_t)s1.x * 32 + c4];
    ushort4 v2 = xb[(size_t)s2.x * 32 + c4];
    ushort4 v3 = xb[(size_t)s3.x * 32 + c4];
    float w0 = -b2f(s0.y), w1 = -b2f(s1.y), w2 = -b2f(s2.y), w3 = -b2f(s3.y);
    a0 = fmaf(w0, b2f(v0.x), a0); a1 = fmaf(w0, b2f(v0.y), a1);
    a2 = fmaf(w0, b2f(v0.z), a2); a3 = fmaf(w0, b2f(v0.w), a3);
    a0 = fmaf(w1, b2f(v1.x), a0); a1 = fmaf(w1, b2f(v1.y), a1);
    a2 = fmaf(w1, b2f(v1.z), a2); a3 = fmaf(w1, b2f(v1.w), a3);
    a0 = fmaf(w2, b2f(v2.x), a0); a1 = fmaf(w2, b2f(v2.y), a1);
    a2 = fmaf(w2, b2f(v2.z), a2); a3 = fmaf(w2, b2f(v2.w), a3);
    a0 = fmaf(w3, b2f(v3.x), a0); a1 = fmaf(w3, b2f(v3.y), a1);
    a2 = fmaf(w3, b2f(v3.z), a2); a3 = fmaf(w3, b2f(v3.w), a3);
  }
  for (; e < end; ++e) {
    ushort2 s0 = sw[e];
    ushort4 v0 = xb[(size_t)s0.x * 32 + c4];
    float w0 = -b2f(s0.y);
    a0 = fmaf(w0, b2f(v0.x), a0); a1 = fmaf(w0, b2f(v0.y), a1);
    a2 = fmaf(w0, b2f(v0.z), a2); a3 = fmaf(w0, b2f(v0.w), a3);
  }
  tx1b[((size_t)conv * N + row) * 32 + c4] =
      make_ushort4(f2b(a0), f2b(a1), f2b(a2), f2b(a3));
}

// Tx2_i = 2*lhat_i(Tx1_i) - x, all convs. 4-edge unroll.
__global__ __launch_bounds__(256) void spmvB_all(const int* __restrict__ row_ptr,
    const ushort2* __restrict__ srcw, const float* __restrict__ diag,
    const ushort4* __restrict__ t1all, const ushort4* __restrict__ xb,
    ushort4* __restrict__ t2all, int N, int E, int NCv) {
  int rg = blockIdx.x * 8 + ((int)threadIdx.x >> 5);
  if (rg >= NCv * N) return;
  int conv = rg / N;
  int row = rg - conv * N;
  const int* rp = row_ptr + (size_t)conv * (N + 1);
  const ushort2* sw = srcw + (size_t)conv * E;
  const ushort4* t1 = t1all + (size_t)conv * N * 32;
  int c4 = threadIdx.x & 31;
  float d = diag[(size_t)conv * N + row];
  ushort4 tv = t1[(size_t)row * 32 + c4];
  float a0 = d * b2f(tv.x), a1 = d * b2f(tv.y);
  float a2 = d * b2f(tv.z), a3 = d * b2f(tv.w);
  int e = rp[row], end = rp[row + 1];
  for (; e + 3 < end; e += 4) {
    ushort2 s0 = sw[e], s1 = sw[e + 1], s2 = sw[e + 2], s3 = sw[e + 3];
    ushort4 v0 = t1[(size_t)s0.x * 32 + c4];
    ushort4 v1 = t1[(size_t)s1.x * 32 + c4];
    ushort4 v2 = t1[(size_t)s2.x * 32 + c4];
    ushort4 v3 = t1[(size_t)s3.x * 32 + c4];
    float w0 = -b2f(s0.y), w1 = -b2f(s1.y), w2 = -b2f(s2.y), w3 = -b2f(s3.y);
    a0 = fmaf(w0, b2f(v0.x), a0); a1 = fmaf(w0, b2f(v0.y), a1);
    a2 = fmaf(w0, b2f(v0.z), a2); a3 = fmaf(w0, b2f(v0.w), a3);
    a0 = fmaf(w1, b2f(v1.x), a0); a1 = fmaf(w1, b2f(v1.y), a1);
    a2 = fmaf(w1, b2f(v1.z), a2); a3 = fmaf(w1, b2f(v1.w), a3);
    a0 = fmaf(w2, b2f(v2.x), a0); a1 = fmaf(w2, b2f(v2.y), a1);
    a2 = fmaf(w2, b2f(v2.z), a2); a3 = fmaf(w2, b2f(v2.w), a3);
    a0 = fmaf(w3, b2f(v3.x), a0); a1 = fmaf(w3, b2f(v3.y), a1);
    a2 = fmaf(w3, b2f(v3.z), a2); a3 = fmaf(w3, b2f(v3.w), a3);
  }
  for (; e < end; ++e) {
    ushort2 s0 = sw[e];
    ushort4 v0 = t1[(size_t)s0.x * 32 + c4];
    float w0 = -b2f(s0.y);
    a0 = fmaf(w0, b2f(v0.x), a0); a1 = fmaf(w0, b2f(v0.y), a1);
    a2 = fmaf(w0, b2f(v0.z), a2); a3 = fmaf(w0, b2f(v0.w), a3);
  }
  ushort4 xv = xb[(size_t)row * 32 + c4];
  a0 = 2.f * a0 - b2f(xv.x); a1 = 2.f * a1 - b2f(xv.y);
  a2 = 2.f * a2 - b2f(xv.z); a3 = 2.f * a3 - b2f(xv.w);
  t2all[((size_t)conv * N + row) * 32 + c4] =
      make_ushort4(f2b(a0), f2b(a1), f2b(a2), f2b(a3));
}

// MFMA GEMM with LDS double-buffered B.
// LDS layout (swizzled): Bl[buf][row*128 + (slot^(row&7))*8] holds
// Wtb[s][row][slot*8..+8]  (slot = 16B k-chunk index, 0..15).
// Staging: thread t, iter i -> row=(t>>4)+i*16, LDS slot'=t&15,
//          global slot = (t&15)^((t>>4)&7)  (row&7 == (t>>4)&7).
// Read: B-frag (nt,kq): row=nt*16+lr, slot=kq*4+lk, LDS slot'=slot^(lr&7).
// One barrier per stage; write-for-s+1 after compute-of-s (race-free: all
// readers of that buffer finished before the barrier at top of stage s).
__global__ __launch_bounds__(256) void gemm_mfma(const unsigned short* __restrict__ xb,
    const unsigned short* __restrict__ t1all, const unsigned short* __restrict__ t2all,
    const unsigned short* __restrict__ Wtb, const float* __restrict__ bs,
    float* __restrict__ C, int N, int NCv) {
  __shared__ unsigned short Bl[2][CDIM * CDIM];
  const int t = threadIdx.x;
  const int wid = t >> 6;
  const int lane = t & 63;
  const int lr = lane & 15;
  const int lk = lane >> 4;
  const int r0 = blockIdx.x * 64 + wid * 16;
  const int stages = 1 + 2 * NCv;

  // staging constants
  const int srow0 = t >> 4;                       // + i*16
  const int wslot = t & 15;
  const int gslot = (t & 15) ^ ((t >> 4) & 7);

  f32x4 acc[8];
  #pragma unroll
  for (int nt = 0; nt < 8; ++nt) acc[nt] = (f32x4){0.f, 0.f, 0.f, 0.f};

  int ra = r0 + lr;
  ra = ra < N ? ra : N - 1;  // clamp: garbage rows only feed unstored D rows

  auto aptr = [&](int s) -> const unsigned short* {
    if (s == 0) return xb;
    if (s & 1) return t1all + (size_t)((s - 1) >> 1) * (size_t)N * CDIM;
    return t2all + (size_t)((s >> 1) - 1) * (size_t)N * CDIM;
  };

  // prologue: stage 0 B into buf0, A-frags for stage 0
  u16x8 stg[8];
  {
    const unsigned short* Ws = Wtb;
    #pragma unroll
    for (int i = 0; i < 8; ++i)
      stg[i] = *(const u16x8*)(Ws + (size_t)(srow0 + i * 16) * CDIM + gslot * 8);
    #pragma unroll
    for (int i = 0; i < 8; ++i)
      *(u16x8*)(&Bl[0][(srow0 + i * 16) * CDIM + wslot * 8]) = stg[i];
  }
  bf16x8 aC[4], aN[4];
  {
    const unsigned short* A0 = aptr(0) + (size_t)ra * CDIM;
    #pragma unroll
    for (int kq = 0; kq < 4; ++kq)
      aC[kq] = *(const bf16x8*)(A0 + kq * 32 + lk * 8);
  }

  for (int s = 0; s < stages; ++s) {
    const int nb = s & 1;
    // issue loads for stage s+1 (B staging + A frags) — hidden under compute
    if (s + 1 < stages) {
      const unsigned short* Ws = Wtb + (size_t)(s + 1) * CDIM * CDIM;
      #pragma unroll
      for (int i = 0; i < 8; ++i)
        stg[i] = *(const u16x8*)(Ws + (size_t)(srow0 + i * 16) * CDIM + gslot * 8);
      const unsigned short* An = aptr(s + 1) + (size_t)ra * CDIM;
      #pragma unroll
      for (int kq = 0; kq < 4; ++kq)
        aN[kq] = *(const bf16x8*)(An + kq * 32 + lk * 8);
    }
    __syncthreads();  // buf[nb] writes (end of prev iter / prologue) visible
    // compute stage s from LDS
    #pragma unroll
    for (int nt = 0; nt < 8; ++nt) {
      const int row = nt * 16 + lr;
      const unsigned short* Bb = &Bl[nb][row * CDIM];
      #pragma unroll
      for (int kq = 0; kq < 4; ++kq) {
        const bf16x8 bf = *(const bf16x8*)(Bb + (((kq * 4 + lk) ^ (lr & 7)) * 8));
        acc[nt] = __builtin_amdgcn_mfma_f32_16x16x32_bf16(aC[kq], bf, acc[nt], 0, 0, 0);
      }
    }
    // write staged B for s+1 into the other buffer; rotate A frags
    if (s + 1 < stages) {
      #pragma unroll
      for (int i = 0; i < 8; ++i)
        *(u16x8*)(&Bl[nb ^ 1][(srow0 + i * 16) * CDIM + wslot * 8]) = stg[i];
      #pragma unroll
      for (int kq = 0; kq < 4; ++kq) aC[kq] = aN[kq];
    }
  }

  const int orow = r0 + lk * 4;
  #pragma unroll
  for (int nt = 0; nt < 8; ++nt) {
    int col = nt * 16 + lr;
    float bb = bs[col];
    #pragma unroll
    for (int reg = 0; reg < 4; ++reg) {
      int r = orow + reg;
      if (r < N) C[(size_t)r * CDIM + col] = acc[nt][reg] + bb;
    }
  }
}

extern "C" void kernel_launch(void* const* d_in, const int* in_sizes, int n_in,
                              void* d_out, int out_size, void* d_ws, size_t ws_size,
                              hipStream_t stream) {
  const float* x  = (const float*)d_in[0];
  const int*   ei = (const int*)d_in[1];    // [NC, 2, E] int32
  const float* ew = (const float*)d_in[2];  // [NC, E]
  const float* W  = (const float*)d_in[3];  // [NC, K, 128, 128]
  const float* b  = (const float*)d_in[4];  // [NC, 128]

  const int Nn  = in_sizes[0] / CDIM;
  const int NCv = in_sizes[4] / CDIM;
  const int E   = in_sizes[2] / NCv;
  const int KK  = in_sizes[3] / (NCv * CDIM * CDIM);
  const int stages = 1 + 2 * NCv;
  const int nr = (Nn + RANGE - 1) / RANGE;

  char* p = (char*)d_ws;
  auto take = [&](size_t bytes) { char* q = p; p += (bytes + 255) & ~(size_t)255; return q; };
  float* diag    = (float*)take((size_t)NCv * Nn * 4);
  int*   row_ptr = (int*)take((size_t)NCv * (Nn + 1) * 4);
  int*   coarse  = (int*)take((size_t)NCv * 2 * MAXNR * 4);
  int*   bases_s = (int*)take((size_t)NCv * (MAXNR + 1) * 4);
  int*   bases_d = (int*)take((size_t)NCv * (MAXNR + 1) * 4);
  int*   cur_s   = (int*)take((size_t)NCv * MAXNR * 4);
  int*   cur_d   = (int*)take((size_t)NCv * MAXNR * 4);
  unsigned short* Wtb = (unsigned short*)take((size_t)stages * CDIM * CDIM * 2);
  float* bs      = (float*)take(CDIM * 4);
  ushort2* xb    = (ushort2*)take((size_t)Nn * 64 * 4);
  ushort2* tx1b  = (ushort2*)take((size_t)NCv * Nn * 64 * 4);
  // tx2b region aliased with the transient D/S bucket buffers:
  // D/S are dead after finalize_kernel; tx2b written only by spmvB_all (later).
  size_t D_bytes  = ((size_t)NCv * E * 8 + 255) & ~(size_t)255;
  size_t S_bytes  = ((size_t)NCv * E * 4 + 255) & ~(size_t)255;
  size_t tx2_bytes = (size_t)NCv * Nn * 64 * 4;
  size_t big_bytes = D_bytes + S_bytes > tx2_bytes ? D_bytes + S_bytes : tx2_bytes;
  char* big = take(big_bytes);
  ushort2* tx2b = (ushort2*)big;
  ushort4* D    = (ushort4*)big;
  ushort2* S    = (ushort2*)(big + D_bytes);
  ushort2* srcw = (ushort2*)take((size_t)NCv * E * 4);

  hipMemsetAsync(coarse, 0, (size_t)NCv * 2 * MAXNR * 4, stream);

  xcast_kernel<<<(Nn * 64 + 255) / 256, 256, 0, stream>>>(
      (const float2*)x, xb, Nn * 64);
  wcast_kernel<<<(stages * CDIM * CDIM + 255) / 256, 256, 0, stream>>>(
      W, b, Wtb, bs, KK, NCv);
  hist_coarse<<<512, 256, 0, stream>>>(ei, coarse, E, NCv, nr);
  scan_coarse<<<1, 64, 0, stream>>>(coarse, bases_s, bases_d, cur_s, cur_d, NCv, nr);

  const int P = 256;
  const int CE = (E + P - 1) / P;
  partition_kernel<<<NCv * P, 256, 0, stream>>>(ei, ew, cur_d, cur_s, D, S,
                                                E, CE, P, NCv, nr);
  finalize_kernel<<<NCv * nr, 512, 0, stream>>>(D, S, bases_d, bases_s,
                                                row_ptr, diag, srcw, E, Nn, NCv, nr);

  spmvA<<<(NCv * Nn + 7) / 8, 256, 0, stream>>>(row_ptr, srcw, diag,
      (const ushort4*)xb, (ushort4*)tx1b, Nn, E, NCv);
  spmvB_all<<<(NCv * Nn + 7) / 8, 256, 0, stream>>>(row_ptr, srcw, diag,
      (const ushort4*)tx1b, (const ushort4*)xb, (ushort4*)tx2b, Nn, E, NCv);

  gemm_mfma<<<(Nn + 63) / 64, 256, 0, stream>>>(
      (const unsigned short*)xb, (const unsigned short*)tx1b,
      (const unsigned short*)tx2b, Wtb, bs, (float*)d_out, Nn, NCv);
}

// Round 10
// 329.477 us; speedup vs baseline: 2.8078x; 1.0275x over previous
//
#include <hip/hip_runtime.h>

// out = Σ_i ChebConv_i(x), K=3, normalization=None, lambda_max=2 (scale=1).
// lhat(v)[r] = (deg[r]-1)*v[r] - Σ_{e:dst=r} w_e v[src_e]
// Tx1 = lhat(x); Tx2 = 2*lhat(Tx1) - x
// out = x@ΣW[i,0] + Σ_i (Tx1_i@W[i,1] + Tx2_i@W[i,2]) + Σ_i b_i
//
// Round 10: spmv MLP 2x (4 rows/wave, 16 lanes x uint4/row; 16 gathers in
// flight) + bit-trick bf16 cvt (AND/SHL per channel, single 16B load/lane).

#define CDIM 128
#define RANGE 512
#define RSH 9
#define MAXNR 128

typedef __attribute__((ext_vector_type(8))) short bf16x8;
typedef __attribute__((ext_vector_type(8))) unsigned short u16x8;
typedef __attribute__((ext_vector_type(4))) float f32x4;

__device__ __forceinline__ float b2f(unsigned short h) {
  return __uint_as_float((unsigned)h << 16);
}
__device__ __forceinline__ unsigned short f2b(float f) {
  unsigned u = __float_as_uint(f);
  return (unsigned short)((u + 0x7FFF + ((u >> 16) & 1)) >> 16);
}
__device__ __forceinline__ float blo(unsigned u) { return __uint_as_float(u << 16); }
__device__ __forceinline__ float bhi(unsigned u) { return __uint_as_float(u & 0xFFFF0000u); }
__device__ __forceinline__ unsigned pk(float lo, float hi) {
  return (unsigned)f2b(lo) | ((unsigned)f2b(hi) << 16);
}

// x (f32) -> xb (bf16 pairs)
__global__ __launch_bounds__(256) void xcast_kernel(const float2* __restrict__ x,
    ushort2* __restrict__ xb, int total2) {
  int i = blockIdx.x * 256 + threadIdx.x;
  if (i >= total2) return;
  float2 v = x[i];
  xb[i] = make_ushort2(f2b(v.x), f2b(v.y));
}

// Wtb[s][n][k] (bf16, transposed weights) for the 1+2*NCv GEMM stages; bs = Σ b_i.
__global__ __launch_bounds__(256) void wcast_kernel(const float* __restrict__ W,
    const float* __restrict__ b, unsigned short* __restrict__ Wtb,
    float* __restrict__ bs, int KK, int NCv) {
  int p = blockIdx.x * 256 + threadIdx.x;
  const int stages = 1 + 2 * NCv;
  if (p < stages * CDIM * CDIM) {
    int s = p >> 14;
    int nk = p & 16383;
    int n = nk >> 7, k = nk & 127;
    float v;
    if (s == 0) {
      v = 0.f;
      for (int i = 0; i < NCv; ++i)
        v += W[(size_t)i * KK * CDIM * CDIM + (size_t)k * CDIM + n];
    } else {
      int i, kk;
      if (s & 1) { i = (s - 1) >> 1; kk = 1; }
      else       { i = (s >> 1) - 1; kk = 2; }
      v = W[(size_t)i * KK * CDIM * CDIM + (size_t)kk * CDIM * CDIM + (size_t)k * CDIM + n];
    }
    Wtb[p] = f2b(v);
  }
  if (p < CDIM) {
    float s = 0.f;
    for (int i = 0; i < NCv; ++i) s += b[i * CDIM + p];
    bs[p] = s;
  }
}

// coarse per-bucket counts of src and dst, LDS-aggregated
__global__ __launch_bounds__(256) void hist_coarse(const int* __restrict__ ei,
    int* __restrict__ coarse, int E, int NCv, int nr) {
  __shared__ int h[2 * MAXNR];
  int t = threadIdx.x;
  int g0 = blockIdx.x * 256 + t;
  int stride = gridDim.x * 256;
  for (int conv = 0; conv < NCv; ++conv) {
    if (t < 2 * MAXNR) h[t] = 0;
    __syncthreads();
    const int* srcv = ei + (size_t)conv * 2 * E;
    const int* dstv = srcv + E;
    for (int e = g0; e < E; e += stride) {
      atomicAdd(&h[srcv[e] >> RSH], 1);
      atomicAdd(&h[MAXNR + (dstv[e] >> RSH)], 1);
    }
    __syncthreads();
    if (t < nr) {
      if (h[t]) atomicAdd(&coarse[(conv * 2 + 0) * MAXNR + t], h[t]);
      if (h[MAXNR + t]) atomicAdd(&coarse[(conv * 2 + 1) * MAXNR + t], h[MAXNR + t]);
    }
    __syncthreads();
  }
}

// tiny serial scans: bases_d/s[conv][0..nr], cursors init = bases
__global__ __launch_bounds__(64) void scan_coarse(const int* __restrict__ coarse,
    int* __restrict__ bases_s, int* __restrict__ bases_d,
    int* __restrict__ cur_s, int* __restrict__ cur_d, int NCv, int nr) {
  int t = threadIdx.x;
  if (t >= NCv * 2) return;
  int conv = t >> 1, ax = t & 1;
  const int* c = coarse + (conv * 2 + ax) * MAXNR;
  int* bases = (ax ? bases_d : bases_s) + conv * (MAXNR + 1);
  int* cur = (ax ? cur_d : cur_s) + conv * MAXNR;
  int acc = 0;
  for (int b = 0; b < nr; ++b) {
    bases[b] = acc; cur[b] = acc; acc += c[b];
  }
  bases[nr] = acc;
}

// partition edges into node-range buckets (see r7/r8)
__global__ __launch_bounds__(256) void partition_kernel(const int* __restrict__ ei,
    const float* __restrict__ ew, int* __restrict__ cur_d, int* __restrict__ cur_s,
    ushort4* __restrict__ D, ushort2* __restrict__ S, int E, int CE, int P,
    int NCv, int nr) {
  __shared__ int ld[MAXNR], ls[MAXNR], cd[MAXNR], cs[MAXNR];
  int conv = blockIdx.x / P;
  int pck = blockIdx.x - conv * P;
  int e0 = pck * CE;
  int e1 = min(E, e0 + CE);
  int t = threadIdx.x;
  const int* srcv = ei + (size_t)conv * 2 * E;
  const int* dstv = srcv + E;
  const float* w = ew + (size_t)conv * E;
  if (t < MAXNR) { ld[t] = 0; ls[t] = 0; }
  __syncthreads();
  for (int e = e0 + t; e < e1; e += 256) {
    atomicAdd(&ld[dstv[e] >> RSH], 1);
    atomicAdd(&ls[srcv[e] >> RSH], 1);
  }
  __syncthreads();
  if (t < nr) {
    cd[t] = ld[t] ? atomicAdd(&cur_d[conv * MAXNR + t], ld[t]) : 0;
    cs[t] = ls[t] ? atomicAdd(&cur_s[conv * MAXNR + t], ls[t]) : 0;
  }
  __syncthreads();
  ushort4* Dc = D + (size_t)conv * E;
  ushort2* Sc = S + (size_t)conv * E;
  for (int e = e0 + t; e < e1; e += 256) {
    int s = srcv[e], d = dstv[e];
    unsigned short wb = f2b(w[e]);
    int pd = atomicAdd(&cd[d >> RSH], 1);
    Dc[pd] = make_ushort4((unsigned short)s, (unsigned short)d, wb, 0);
    int ps = atomicAdd(&cs[s >> RSH], 1);
    Sc[ps] = make_ushort2((unsigned short)s, wb);
  }
}

// per (conv, bucket): LDS fine hist + deg; block scan; write row_ptr/diag/CSR.
__global__ __launch_bounds__(512) void finalize_kernel(const ushort4* __restrict__ D,
    const ushort2* __restrict__ S, const int* __restrict__ bases_d,
    const int* __restrict__ bases_s, int* __restrict__ row_ptr,
    float* __restrict__ diag, ushort2* __restrict__ srcw, int E, int N,
    int NCv, int nr) {
  __shared__ unsigned int hist[RANGE];
  __shared__ float fdeg[RANGE];
  __shared__ unsigned int wls[8];
  int conv = blockIdx.x / nr;
  int b = blockIdx.x - conv * nr;
  int t = threadIdx.x;
  hist[t] = 0u; fdeg[t] = 0.f;
  __syncthreads();
  int db0 = bases_d[conv * (MAXNR + 1) + b], db1 = bases_d[conv * (MAXNR + 1) + b + 1];
  int sb0 = bases_s[conv * (MAXNR + 1) + b], sb1 = bases_s[conv * (MAXNR + 1) + b + 1];
  const ushort4* Dc = D + (size_t)conv * E;
  const ushort2* Sc = S + (size_t)conv * E;
  for (int i = db0 + t; i < db1; i += 512)
    atomicAdd(&hist[Dc[i].y & (RANGE - 1)], 1u);
  for (int i = sb0 + t; i < sb1; i += 512) {
    ushort2 r = Sc[i];
    atomicAdd(&fdeg[r.x & (RANGE - 1)], b2f(r.y));
  }
  __syncthreads();
  unsigned int v = hist[t];
  int lane = t & 63, wid = t >> 6;
  unsigned int incl = v;
  #pragma unroll
  for (int off = 1; off < 64; off <<= 1) {
    unsigned int tmp = __shfl_up((int)incl, off, 64);
    if (lane >= off) incl += tmp;
  }
  if (lane == 63) wls[wid] = incl;
  __syncthreads();
  if (wid == 0) {
    unsigned int x = (lane < 8) ? wls[lane] : 0u;
    #pragma unroll
    for (int off = 1; off < 8; off <<= 1) {
      unsigned int tmp = __shfl_up((int)x, off, 64);
      if (lane >= off) x += tmp;
    }
    if (lane < 8) wls[lane] = x;
  }
  __syncthreads();
  unsigned int excl = (wid ? wls[wid - 1] : 0u) + (incl - v);
  hist[t] = excl;
  __syncthreads();
  int n0 = b << RSH;
  int* rp = row_ptr + (size_t)conv * (N + 1);
  float* dg = diag + (size_t)conv * N;
  int n = n0 + t;
  if (n < N) {
    rp[n] = db0 + (int)excl;
    dg[n] = fdeg[t] - 1.0f;
  }
  if (b == nr - 1 && t == 0) rp[N] = E;
  __syncthreads();
  ushort2* swc = srcw + (size_t)conv * E;
  for (int i = db0 + t; i < db1; i += 512) {
    ushort4 r = Dc[i];
    unsigned int pos = atomicAdd(&hist[r.y & (RANGE - 1)], 1u);
    swc[db0 + (int)pos] = make_ushort2(r.x, r.z);
  }
}

// Tx1_i = lhat_i(x), all convs. 4 rows/wave: 16 lanes x uint4 (8 ch) per row.
__global__ __launch_bounds__(256) void spmvA(const int* __restrict__ row_ptr,
    const ushort2* __restrict__ srcw, const float* __restrict__ diag,
    const uint4* __restrict__ xb, uint4* __restrict__ tx1b, int N, int E, int NCv) {
  int rg = blockIdx.x * 16 + ((int)threadIdx.x >> 4);
  if (rg >= NCv * N) return;
  int conv = rg / N;
  int row = rg - conv * N;
  const int* rp = row_ptr + (size_t)conv * (N + 1);
  const ushort2* sw = srcw + (size_t)conv * E;
  int c8 = threadIdx.x & 15;
  float d = diag[(size_t)conv * N + row];
  uint4 xv = xb[(size_t)row * 16 + c8];
  float a0 = d * blo(xv.x), a1 = d * bhi(xv.x);
  float a2 = d * blo(xv.y), a3 = d * bhi(xv.y);
  float a4 = d * blo(xv.z), a5 = d * bhi(xv.z);
  float a6 = d * blo(xv.w), a7 = d * bhi(xv.w);
  int e = rp[row], end = rp[row + 1];
  for (; e + 3 < end; e += 4) {
    ushort2 s0 = sw[e], s1 = sw[e + 1], s2 = sw[e + 2], s3 = sw[e + 3];
    uint4 v0 = xb[(size_t)s0.x * 16 + c8];
    uint4 v1 = xb[(size_t)s1.x * 16 + c8];
    uint4 v2 = xb[(size_t)s2.x * 16 + c8];
    uint4 v3 = xb[(size_t)s3.x * 16 + c8];
    float w0 = -b2f(s0.y), w1 = -b2f(s1.y), w2 = -b2f(s2.y), w3 = -b2f(s3.y);
    a0 = fmaf(w0, blo(v0.x), a0); a1 = fmaf(w0, bhi(v0.x), a1);
    a2 = fmaf(w0, blo(v0.y), a2); a3 = fmaf(w0, bhi(v0.y), a3);
    a4 = fmaf(w0, blo(v0.z), a4); a5 = fmaf(w0, bhi(v0.z), a5);
    a6 = fmaf(w0, blo(v0.w), a6); a7 = fmaf(w0, bhi(v0.w), a7);
    a0 = fmaf(w1, blo(v1.x), a0); a1 = fmaf(w1, bhi(v1.x), a1);
    a2 = fmaf(w1, blo(v1.y), a2); a3 = fmaf(w1, bhi(v1.y), a3);
    a4 = fmaf(w1, blo(v1.z), a4); a5 = fmaf(w1, bhi(v1.z), a5);
    a6 = fmaf(w1, blo(v1.w), a6); a7 = fmaf(w1, bhi(v1.w), a7);
    a0 = fmaf(w2, blo(v2.x), a0); a1 = fmaf(w2, bhi(v2.x), a1);
    a2 = fmaf(w2, blo(v2.y), a2); a3 = fmaf(w2, bhi(v2.y), a3);
    a4 = fmaf(w2, blo(v2.z), a4); a5 = fmaf(w2, bhi(v2.z), a5);
    a6 = fmaf(w2, blo(v2.w), a6); a7 = fmaf(w2, bhi(v2.w), a7);
    a0 = fmaf(w3, blo(v3.x), a0); a1 = fmaf(w3, bhi(v3.x), a1);
    a2 = fmaf(w3, blo(v3.y), a2); a3 = fmaf(w3, bhi(v3.y), a3);
    a4 = fmaf(w3, blo(v3.z), a4); a5 = fmaf(w3, bhi(v3.z), a5);
    a6 = fmaf(w3, blo(v3.w), a6); a7 = fmaf(w3, bhi(v3.w), a7);
  }
  for (; e < end; ++e) {
    ushort2 s0 = sw[e];
    uint4 v0 = xb[(size_t)s0.x * 16 + c8];
    float w0 = -b2f(s0.y);
    a0 = fmaf(w0, blo(v0.x), a0); a1 = fmaf(w0, bhi(v0.x), a1);
    a2 = fmaf(w0, blo(v0.y), a2); a3 = fmaf(w0, bhi(v0.y), a3);
    a4 = fmaf(w0, blo(v0.z), a4); a5 = fmaf(w0, bhi(v0.z), a5);
    a6 = fmaf(w0, blo(v0.w), a6); a7 = fmaf(w0, bhi(v0.w), a7);
  }
  tx1b[((size_t)conv * N + row) * 16 + c8] =
      make_uint4(pk(a0, a1), pk(a2, a3), pk(a4, a5), pk(a6, a7));
}

// Tx2_i = 2*lhat_i(Tx1_i) - x, all convs. Same 4 rows/wave layout.
__global__ __launch_bounds__(256) void spmvB_all(const int* __restrict__ row_ptr,
    const ushort2* __restrict__ srcw, const float* __restrict__ diag,
    const uint4* __restrict__ t1all, const uint4* __restrict__ xb,
    uint4* __restrict__ t2all, int N, int E, int NCv) {
  int rg = blockIdx.x * 16 + ((int)threadIdx.x >> 4);
  if (rg >= NCv * N) return;
  int conv = rg / N;
  int row = rg - conv * N;
  const int* rp = row_ptr + (size_t)conv * (N + 1);
  const ushort2* sw = srcw + (size_t)conv * E;
  const uint4* t1 = t1all + (size_t)conv * N * 16;
  int c8 = threadIdx.x & 15;
  float d = diag[(size_t)conv * N + row];
  uint4 tv = t1[(size_t)row * 16 + c8];
  float a0 = d * blo(tv.x), a1 = d * bhi(tv.x);
  float a2 = d * blo(tv.y), a3 = d * bhi(tv.y);
  float a4 = d * blo(tv.z), a5 = d * bhi(tv.z);
  float a6 = d * blo(tv.w), a7 = d * bhi(tv.w);
  int e = rp[row], end = rp[row + 1];
  for (; e + 3 < end; e += 4) {
    ushort2 s0 = sw[e], s1 = sw[e + 1], s2 = sw[e + 2], s3 = sw[e + 3];
    uint4 v0 = t1[(size_t)s0.x * 16 + c8];
    uint4 v1 = t1[(size_t)s1.x * 16 + c8];
    uint4 v2 = t1[(size_t)s2.x * 16 + c8];
    uint4 v3 = t1[(size_t)s3.x * 16 + c8];
    float w0 = -b2f(s0.y), w1 = -b2f(s1.y), w2 = -b2f(s2.y), w3 = -b2f(s3.y);
    a0 = fmaf(w0, blo(v0.x), a0); a1 = fmaf(w0, bhi(v0.x), a1);
    a2 = fmaf(w0, blo(v0.y), a2); a3 = fmaf(w0, bhi(v0.y), a3);
    a4 = fmaf(w0, blo(v0.z), a4); a5 = fmaf(w0, bhi(v0.z), a5);
    a6 = fmaf(w0, blo(v0.w), a6); a7 = fmaf(w0, bhi(v0.w), a7);
    a0 = fmaf(w1, blo(v1.x), a0); a1 = fmaf(w1, bhi(v1.x), a1);
    a2 = fmaf(w1, blo(v1.y), a2); a3 = fmaf(w1, bhi(v1.y), a3);
    a4 = fmaf(w1, blo(v1.z), a4); a5 = fmaf(w1, bhi(v1.z), a5);
    a6 = fmaf(w1, blo(v1.w), a6); a7 = fmaf(w1, bhi(v1.w), a7);
    a0 = fmaf(w2, blo(v2.x), a0); a1 = fmaf(w2, bhi(v2.x), a1);
    a2 = fmaf(w2, blo(v2.y), a2); a3 = fmaf(w2, bhi(v2.y), a3);
    a4 = fmaf(w2, blo(v2.z), a4); a5 = fmaf(w2, bhi(v2.z), a5);
    a6 = fmaf(w2, blo(v2.w), a6); a7 = fmaf(w2, bhi(v2.w), a7);
    a0 = fmaf(w3, blo(v3.x), a0); a1 = fmaf(w3, bhi(v3.x), a1);
    a2 = fmaf(w3, blo(v3.y), a2); a3 = fmaf(w3, bhi(v3.y), a3);
    a4 = fmaf(w3, blo(v3.z), a4); a5 = fmaf(w3, bhi(v3.z), a5);
    a6 = fmaf(w3, blo(v3.w), a6); a7 = fmaf(w3, bhi(v3.w), a7);
  }
  for (; e < end; ++e) {
    ushort2 s0 = sw[e];
    uint4 v0 = t1[(size_t)s0.x * 16 + c8];
    float w0 = -b2f(s0.y);
    a0 = fmaf(w0, blo(v0.x), a0); a1 = fmaf(w0, bhi(v0.x), a1);
    a2 = fmaf(w0, blo(v0.y), a2); a3 = fmaf(w0, bhi(v0.y), a3);
    a4 = fmaf(w0, blo(v0.z), a4); a5 = fmaf(w0, bhi(v0.z), a5);
    a6 = fmaf(w0, blo(v0.w), a6); a7 = fmaf(w0, bhi(v0.w), a7);
  }
  uint4 xv = xb[(size_t)row * 16 + c8];
  a0 = 2.f * a0 - blo(xv.x); a1 = 2.f * a1 - bhi(xv.x);
  a2 = 2.f * a2 - blo(xv.y); a3 = 2.f * a3 - bhi(xv.y);
  a4 = 2.f * a4 - blo(xv.z); a5 = 2.f * a5 - bhi(xv.z);
  a6 = 2.f * a6 - blo(xv.w); a7 = 2.f * a7 - bhi(xv.w);
  t2all[((size_t)conv * N + row) * 16 + c8] =
      make_uint4(pk(a0, a1), pk(a2, a3), pk(a4, a5), pk(a6, a7));
}

// MFMA GEMM with LDS double-buffered B (r9, verified).
__global__ __launch_bounds__(256) void gemm_mfma(const unsigned short* __restrict__ xb,
    const unsigned short* __restrict__ t1all, const unsigned short* __restrict__ t2all,
    const unsigned short* __restrict__ Wtb, const float* __restrict__ bs,
    float* __restrict__ C, int N, int NCv) {
  __shared__ unsigned short Bl[2][CDIM * CDIM];
  const int t = threadIdx.x;
  const int wid = t >> 6;
  const int lane = t & 63;
  const int lr = lane & 15;
  const int lk = lane >> 4;
  const int r0 = blockIdx.x * 64 + wid * 16;
  const int stages = 1 + 2 * NCv;

  const int srow0 = t >> 4;
  const int wslot = t & 15;
  const int gslot = (t & 15) ^ ((t >> 4) & 7);

  f32x4 acc[8];
  #pragma unroll
  for (int nt = 0; nt < 8; ++nt) acc[nt] = (f32x4){0.f, 0.f, 0.f, 0.f};

  int ra = r0 + lr;
  ra = ra < N ? ra : N - 1;

  auto aptr = [&](int s) -> const unsigned short* {
    if (s == 0) return xb;
    if (s & 1) return t1all + (size_t)((s - 1) >> 1) * (size_t)N * CDIM;
    return t2all + (size_t)((s >> 1) - 1) * (size_t)N * CDIM;
  };

  u16x8 stg[8];
  {
    const unsigned short* Ws = Wtb;
    #pragma unroll
    for (int i = 0; i < 8; ++i)
      stg[i] = *(const u16x8*)(Ws + (size_t)(srow0 + i * 16) * CDIM + gslot * 8);
    #pragma unroll
    for (int i = 0; i < 8; ++i)
      *(u16x8*)(&Bl[0][(srow0 + i * 16) * CDIM + wslot * 8]) = stg[i];
  }
  bf16x8 aC[4], aN[4];
  {
    const unsigned short* A0 = aptr(0) + (size_t)ra * CDIM;
    #pragma unroll
    for (int kq = 0; kq < 4; ++kq)
      aC[kq] = *(const bf16x8*)(A0 + kq * 32 + lk * 8);
  }

  for (int s = 0; s < stages; ++s) {
    const int nb = s & 1;
    if (s + 1 < stages) {
      const unsigned short* Ws = Wtb + (size_t)(s + 1) * CDIM * CDIM;
      #pragma unroll
      for (int i = 0; i < 8; ++i)
        stg[i] = *(const u16x8*)(Ws + (size_t)(srow0 + i * 16) * CDIM + gslot * 8);
      const unsigned short* An = aptr(s + 1) + (size_t)ra * CDIM;
      #pragma unroll
      for (int kq = 0; kq < 4; ++kq)
        aN[kq] = *(const bf16x8*)(An + kq * 32 + lk * 8);
    }
    __syncthreads();
    #pragma unroll
    for (int nt = 0; nt < 8; ++nt) {
      const int row = nt * 16 + lr;
      const unsigned short* Bb = &Bl[nb][row * CDIM];
      #pragma unroll
      for (int kq = 0; kq < 4; ++kq) {
        const bf16x8 bf = *(const bf16x8*)(Bb + (((kq * 4 + lk) ^ (lr & 7)) * 8));
        acc[nt] = __builtin_amdgcn_mfma_f32_16x16x32_bf16(aC[kq], bf, acc[nt], 0, 0, 0);
      }
    }
    if (s + 1 < stages) {
      #pragma unroll
      for (int i = 0; i < 8; ++i)
        *(u16x8*)(&Bl[nb ^ 1][(srow0 + i * 16) * CDIM + wslot * 8]) = stg[i];
      #pragma unroll
      for (int kq = 0; kq < 4; ++kq) aC[kq] = aN[kq];
    }
  }

  const int orow = r0 + lk * 4;
  #pragma unroll
  for (int nt = 0; nt < 8; ++nt) {
    int col = nt * 16 + lr;
    float bb = bs[col];
    #pragma unroll
    for (int reg = 0; reg < 4; ++reg) {
      int r = orow + reg;
      if (r < N) C[(size_t)r * CDIM + col] = acc[nt][reg] + bb;
    }
  }
}

extern "C" void kernel_launch(void* const* d_in, const int* in_sizes, int n_in,
                              void* d_out, int out_size, void* d_ws, size_t ws_size,
                              hipStream_t stream) {
  const float* x  = (const float*)d_in[0];
  const int*   ei = (const int*)d_in[1];    // [NC, 2, E] int32
  const float* ew = (const float*)d_in[2];  // [NC, E]
  const float* W  = (const float*)d_in[3];  // [NC, K, 128, 128]
  const float* b  = (const float*)d_in[4];  // [NC, 128]

  const int Nn  = in_sizes[0] / CDIM;
  const int NCv = in_sizes[4] / CDIM;
  const int E   = in_sizes[2] / NCv;
  const int KK  = in_sizes[3] / (NCv * CDIM * CDIM);
  const int stages = 1 + 2 * NCv;
  const int nr = (Nn + RANGE - 1) / RANGE;

  char* p = (char*)d_ws;
  auto take = [&](size_t bytes) { char* q = p; p += (bytes + 255) & ~(size_t)255; return q; };
  float* diag    = (float*)take((size_t)NCv * Nn * 4);
  int*   row_ptr = (int*)take((size_t)NCv * (Nn + 1) * 4);
  int*   coarse  = (int*)take((size_t)NCv * 2 * MAXNR * 4);
  int*   bases_s = (int*)take((size_t)NCv * (MAXNR + 1) * 4);
  int*   bases_d = (int*)take((size_t)NCv * (MAXNR + 1) * 4);
  int*   cur_s   = (int*)take((size_t)NCv * MAXNR * 4);
  int*   cur_d   = (int*)take((size_t)NCv * MAXNR * 4);
  unsigned short* Wtb = (unsigned short*)take((size_t)stages * CDIM * CDIM * 2);
  float* bs      = (float*)take(CDIM * 4);
  ushort2* xb    = (ushort2*)take((size_t)Nn * 64 * 4);
  ushort2* tx1b  = (ushort2*)take((size_t)NCv * Nn * 64 * 4);
  size_t D_bytes  = ((size_t)NCv * E * 8 + 255) & ~(size_t)255;
  size_t S_bytes  = ((size_t)NCv * E * 4 + 255) & ~(size_t)255;
  size_t tx2_bytes = (size_t)NCv * Nn * 64 * 4;
  size_t big_bytes = D_bytes + S_bytes > tx2_bytes ? D_bytes + S_bytes : tx2_bytes;
  char* big = take(big_bytes);
  ushort2* tx2b = (ushort2*)big;
  ushort4* D    = (ushort4*)big;
  ushort2* S    = (ushort2*)(big + D_bytes);
  ushort2* srcw = (ushort2*)take((size_t)NCv * E * 4);

  hipMemsetAsync(coarse, 0, (size_t)NCv * 2 * MAXNR * 4, stream);

  xcast_kernel<<<(Nn * 64 + 255) / 256, 256, 0, stream>>>(
      (const float2*)x, xb, Nn * 64);
  wcast_kernel<<<(stages * CDIM * CDIM + 255) / 256, 256, 0, stream>>>(
      W, b, Wtb, bs, KK, NCv);
  hist_coarse<<<512, 256, 0, stream>>>(ei, coarse, E, NCv, nr);
  scan_coarse<<<1, 64, 0, stream>>>(coarse, bases_s, bases_d, cur_s, cur_d, NCv, nr);

  const int P = 256;
  const int CE = (E + P - 1) / P;
  partition_kernel<<<NCv * P, 256, 0, stream>>>(ei, ew, cur_d, cur_s, D, S,
                                                E, CE, P, NCv, nr);
  finalize_kernel<<<NCv * nr, 512, 0, stream>>>(D, S, bases_d, bases_s,
                                                row_ptr, diag, srcw, E, Nn, NCv, nr);

  spmvA<<<(NCv * Nn + 15) / 16, 256, 0, stream>>>(row_ptr, srcw, diag,
      (const uint4*)xb, (uint4*)tx1b, Nn, E, NCv);
  spmvB_all<<<(NCv * Nn + 15) / 16, 256, 0, stream>>>(row_ptr, srcw, diag,
      (const uint4*)tx1b, (const uint4*)xb, (uint4*)tx2b, Nn, E, NCv);

  gemm_mfma<<<(Nn + 63) / 64, 256, 0, stream>>>(
      (const unsigned short*)xb, (const unsigned short*)tx1b,
      (const unsigned short*)tx2b, Wtb, bs, (float*)d_out, Nn, NCv);
}